// Round 18
// baseline (1214.492 us; speedup 1.0000x reference)
//
#include <hip/hip_runtime.h>
#include <hip/hip_bf16.h>

// ---------------- problem constants (match setup_inputs) ----------------
#define T_TOK 4096
#define H_DIM 1024
#define E_NUM 8
#define I_DIM 3584
#define NPAIR (T_TOK * 2)   // top_k = 2
#define MAX_RT 72           // worst-case total row tiles: sum ceil(cnt_e/128) <= 64+7

#define BM 128
#define BN 128
#define BK 64
#define G0_NWG (MAX_RT * (I_DIM / BN))   // 2016 gemm0 blocks
#define WT_NB 3584                       // w2 dual-tile transpose blocks
#define G1_NWG (MAX_RT * (H_DIM / BN))   // 576 gemm1 blocks

typedef __attribute__((ext_vector_type(8))) short bf16x8;
typedef __attribute__((ext_vector_type(4))) float f32x4;
typedef __attribute__((ext_vector_type(8))) unsigned short ushort8_t;
typedef __attribute__((ext_vector_type(4))) unsigned short ushort4_t;

// RNE fp32 -> bf16
__device__ __forceinline__ unsigned short f2bf(float x) {
  unsigned int u = __float_as_uint(x);
  unsigned int r = (u + 0x7FFFu + ((u >> 16) & 1u)) >> 16;
  return (unsigned short)r;
}

// async 16B global -> LDS (dest: wave-uniform base, HW adds lane*16)
__device__ __forceinline__ void gload16(const void* g, unsigned short* l) {
  __builtin_amdgcn_global_load_lds(
      (const __attribute__((address_space(1))) void*)g,
      (__attribute__((address_space(3))) void*)l, 16, 0, 0);
}

// ---------------- dual-tile transpose (2x 64-row passes, fused 256B writes) -
__device__ __forceinline__ void transpose_body2(const float* __restrict__ src,
                                                unsigned short* __restrict__ dst,
                                                int R, int C, int e, int c0, int r0,
                                                char* smem) {
  float (*tile)[65] = reinterpret_cast<float (*)[65]>(smem);
  const float* s = src + (size_t)e * R * C;
  unsigned short* d = dst + (size_t)e * R * C;
  const int th = threadIdx.x;
  const int tr = th >> 4;
  const int tc4 = (th & 15) * 4;
  const int wc = th >> 3;
  const int wr = (th & 7) * 8;
  ushort8_t oA[2];
#pragma unroll
  for (int it = 0; it < 4; ++it) {
    const int r = it * 16 + tr;
    float4 v = *reinterpret_cast<const float4*>(s + (size_t)(r0 + r) * C + c0 + tc4);
    tile[r][tc4] = v.x; tile[r][tc4 + 1] = v.y; tile[r][tc4 + 2] = v.z; tile[r][tc4 + 3] = v.w;
  }
  __syncthreads();
#pragma unroll
  for (int it = 0; it < 2; ++it) {
    const int c = it * 32 + wc;
#pragma unroll
    for (int j = 0; j < 8; ++j) oA[it][j] = f2bf(tile[wr + j][c]);
  }
  __syncthreads();
#pragma unroll
  for (int it = 0; it < 4; ++it) {
    const int r = it * 16 + tr;
    float4 v = *reinterpret_cast<const float4*>(s + (size_t)(r0 + 64 + r) * C + c0 + tc4);
    tile[r][tc4] = v.x; tile[r][tc4 + 1] = v.y; tile[r][tc4 + 2] = v.z; tile[r][tc4 + 3] = v.w;
  }
  __syncthreads();
#pragma unroll
  for (int it = 0; it < 2; ++it) {
    const int c = it * 32 + wc;
    ushort8_t oB;
#pragma unroll
    for (int j = 0; j < 8; ++j) oB[j] = f2bf(tile[wr + j][c]);
    *reinterpret_cast<ushort8_t*>(d + (size_t)(c0 + c) * R + r0 + wr) = oA[it];
    *reinterpret_cast<ushort8_t*>(d + (size_t)(c0 + c) * R + r0 + 64 + wr) = oB;
  }
}

__device__ __forceinline__ void router_body(const float* __restrict__ hs,
                                            const float* __restrict__ gw,
                                            unsigned short* __restrict__ hsb,
                                            int* __restrict__ eid, float* __restrict__ wgt,
                                            int* __restrict__ counts, int rbid, char* smem) {
  float* s_gw = reinterpret_cast<float*>(smem);          // 32 KB
  int* s_cnt = reinterpret_cast<int*>(smem + 32768);     // 32 B
  const int th = threadIdx.x;
  for (int u = th; u < 2048; u += 256) {
    const f32x4 v = *reinterpret_cast<const f32x4*>(gw + u * 4);
    *reinterpret_cast<f32x4*>(&s_gw[(u ^ ((u >> 3) & 7)) * 4]) = v;
  }
  if (th < E_NUM) s_cnt[th] = 0;
  __syncthreads();

  const int l = th & 63, w = th >> 6;
#pragma unroll 1
  for (int tt = 0; tt < 4; ++tt) {
    const int t = rbid * 16 + w * 4 + tt;
    const float* hrow = hs + (size_t)t * H_DIM;
    unsigned short* brow = hsb + (size_t)t * H_DIM;
    float acc[E_NUM];
#pragma unroll
    for (int e = 0; e < E_NUM; ++e) acc[e] = 0.f;
#pragma unroll
    for (int i = 0; i < 4; ++i) {
      const int h0 = i * 256 + l * 4;
      const f32x4 x = *reinterpret_cast<const f32x4*>(hrow + h0);
      ushort4_t o = { f2bf(x[0]), f2bf(x[1]), f2bf(x[2]), f2bf(x[3]) };
      *reinterpret_cast<ushort4_t*>(brow + h0) = o;
#pragma unroll
      for (int j = 0; j < 4; ++j) {
        const int h = h0 + j;
        const int p0 = (h * 2) ^ ((h >> 2) & 7);
        const f32x4 g0 = *reinterpret_cast<const f32x4*>(&s_gw[p0 * 4]);
        const f32x4 g1 = *reinterpret_cast<const f32x4*>(&s_gw[(p0 ^ 1) * 4]);
        acc[0] += x[j] * g0[0]; acc[1] += x[j] * g0[1];
        acc[2] += x[j] * g0[2]; acc[3] += x[j] * g0[3];
        acc[4] += x[j] * g1[0]; acc[5] += x[j] * g1[1];
        acc[6] += x[j] * g1[2]; acc[7] += x[j] * g1[3];
      }
    }
#pragma unroll
    for (int e = 0; e < E_NUM; ++e) {
#pragma unroll
      for (int off = 1; off < 64; off <<= 1) acc[e] += __shfl_xor(acc[e], off);
    }
    if (l == 0) {
      int i1 = 0;
#pragma unroll
      for (int e = 1; e < E_NUM; ++e) if (acc[e] > acc[i1]) i1 = e;
      int i2 = (i1 == 0) ? 1 : 0;
#pragma unroll
      for (int e = 0; e < E_NUM; ++e) if (e != i1 && acc[e] > acc[i2]) i2 = e;
      const float e2 = __expf(acc[i2] - acc[i1]);
      const float inv = 1.f / (1.f + e2);
      eid[t * 2] = i1;     wgt[t * 2] = inv;
      eid[t * 2 + 1] = i2; wgt[t * 2 + 1] = e2 * inv;
      atomicAdd(&s_cnt[i1], 1);
      atomicAdd(&s_cnt[i2], 1);
    }
  }
  __syncthreads();
  if (th < E_NUM && s_cnt[th] > 0) atomicAdd(&counts[th], s_cnt[th]);
}

// ---- kernel1: router (bids 0..255) + w1 dual-transpose (256..3839) --------
__global__ __launch_bounds__(256) void prep1_kernel(
    const float* __restrict__ w1, const float* __restrict__ hs,
    const float* __restrict__ gw,
    unsigned short* __restrict__ w1t, unsigned short* __restrict__ hsb,
    int* __restrict__ eid, float* __restrict__ wgt, int* __restrict__ counts) {
  __shared__ char smem[33024];
  const int bid = blockIdx.x;
  if (bid < 256) {
    router_body(hs, gw, hsb, eid, wgt, counts, bid, smem);
    return;
  }
  const int idx = bid - 256;     // w1: R=1024, C=3584; 56c x 8 row-pairs per e
  const int e = idx / 448, rem = idx % 448;
  transpose_body2(w1, w1t, H_DIM, I_DIM, e, (rem % 56) * 64, (rem / 56) * 128, smem);
}

// ---------------- scatter: block-local histogram + range reservation -------
__global__ void scatter_kernel(const int* __restrict__ eid, const int* __restrict__ counts,
                               int* __restrict__ fill, int* __restrict__ rowmap) {
  __shared__ int hist[E_NUM], base[E_NUM];
  const int th = threadIdx.x;
  const int p = blockIdx.x * 256 + th;
  if (th < E_NUM) hist[th] = 0;
  __syncthreads();
  const int e = eid[p];
  const int rloc = atomicAdd(&hist[e], 1);
  __syncthreads();
  if (th < E_NUM) base[th] = (hist[th] > 0) ? atomicAdd(&fill[th], hist[th]) : 0;
  __syncthreads();
  int off = 0;
#pragma unroll
  for (int i = 0; i < E_NUM; ++i) off += (i < e) ? counts[i] : 0;
  rowmap[off + base[e] + rloc] = p;
}

// ---- fused post-scatter kernel: gemm0 | w2 transpose | gemm1 --------------
// bids [0,2016): gemm0 (supertiled; publishes ready[rt] after act tile)
// bids [2016,5600): w2 dual-transpose (publishes flags[72] counter)
// bids [5600,6176): gemm1 (spins for w2t + ready[rt]; atomicAdd into out)
// Deadlock-free: 576 consumers < 1024 co-residency slots -> producers always
// make progress regardless of dispatch order (G16-safe).
__global__ __launch_bounds__(256, 4) void fused_moe_kernel(
    const unsigned short* __restrict__ hsb, const unsigned short* __restrict__ w1t,
    unsigned short* __restrict__ act,
    const float* __restrict__ w2, unsigned short* __restrict__ w2t,
    float* __restrict__ out,
    const int* __restrict__ counts, const int* __restrict__ rowmap,
    const float* __restrict__ wgt, int* __restrict__ flags) {
  __shared__ char smem[(BM * BK + BN * BK) * 2 + BM * 8];   // 33 KB
  const int bid = blockIdx.x;

  // ---------------- w2 transpose producers ----------------
  if (bid >= G0_NWG && bid < G0_NWG + WT_NB) {
    const int idx = bid - G0_NWG;  // w2: R=3584, C=1024; 16c x 28 row-pairs/e
    const int e = idx / 448, rem = idx % 448;
    transpose_body2(w2, w2t, I_DIM, H_DIM, e, (rem % 16) * 64, (rem / 16) * 128, smem);
    __threadfence();
    __syncthreads();
    if (threadIdx.x == 0) atomicAdd(&flags[MAX_RT], 1);
    return;
  }

  unsigned short* As = reinterpret_cast<unsigned short*>(smem);
  unsigned short* Bs = As + BM * BK;
  int* s_pair = reinterpret_cast<int*>(Bs + BN * BK);
  float* s_w = reinterpret_cast<float*>(s_pair + BM);

  const bool is_g1 = (bid >= G0_NWG + WT_NB);
  const int th = threadIdx.x;
  const int lane = th & 63, wid = th >> 6;

  int rt, ct;
  if (!is_g1) {
    // gemm0: T1 swizzle + 9rt x 4ct supertile (A 2.3MB + B 1MB in L2)
    constexpr int CHUNK = G0_NWG / 8;   // 252
    const int wgid = (bid & 7) * CHUNK + (bid >> 3);
    const int l = wgid % CHUNK;
    const int sg = l / 36;
    const int q = l % 36;
    rt = (wgid / CHUNK) * 9 + q % 9;
    ct = sg * 4 + q / 9;
  } else {
    // gemm1: T1 swizzle + band of 2rt x 8ct within each 72-wgid chunk
    constexpr int CHUNK = G1_NWG / 8;   // 72
    const int b1 = bid - (G0_NWG + WT_NB);
    const int wgid = (b1 & 7) * CHUNK + (b1 >> 3);
    const int c9 = (wgid / CHUNK) * 9;
    const int l = wgid % CHUNK;
    if (l < 64) {
      const int band = l >> 4, inner = l & 15;
      rt = c9 + band * 2 + (inner & 1);
      ct = inner >> 1;
    } else {
      rt = c9 + 8;
      ct = l - 64;
    }
  }

  // expert walk from counts (prefix on the fly)
  int e = -1, loc_rt = 0, off_e = 0, cnt = 0;
  {
    int acc_t = 0, off = 0;
#pragma unroll
    for (int ee = 0; ee < E_NUM; ++ee) {
      const int c = counts[ee];
      const int nt = (c + BM - 1) >> 7;
      if (e < 0 && rt < acc_t + nt) { e = ee; loc_rt = rt - acc_t; off_e = off; cnt = c; }
      acc_t += nt; off += c;
    }
  }
  if (e < 0) return;

  // gemm1: wait for w2t complete + this rt's act tiles (28 gemm0 blocks)
  if (is_g1) {
    if (th == 0) {
      while (__hip_atomic_load(&flags[MAX_RT], __ATOMIC_ACQUIRE,
                               __HIP_MEMORY_SCOPE_AGENT) < WT_NB)
        __builtin_amdgcn_s_sleep(8);
      while (__hip_atomic_load(&flags[rt], __ATOMIC_ACQUIRE,
                               __HIP_MEMORY_SCOPE_AGENT) < (I_DIM / BN))
        __builtin_amdgcn_s_sleep(8);
    }
    __syncthreads();
  }

  const int cnt_local = min(BM, cnt - loc_rt * BM);
  const int r_base = off_e + loc_rt * BM;
  constexpr int KD0 = H_DIM;

  if (is_g1 && th < BM) {
    int r = loc_rt * BM + th;
    if (r >= cnt) r = cnt - 1;
    const int p = rowmap[off_e + r];
    s_pair[th] = p;
    s_w[th] = wgt[p];
  }

  const int KD = is_g1 ? I_DIM : KD0;
  const int n0 = ct * BN;
  const unsigned short* wsrc = is_g1 ? w2t : w1t;
  const unsigned short* wbase =
      wsrc + (size_t)e * ((size_t)I_DIM * H_DIM) + (size_t)n0 * KD;

  // staging: LDS dest linear; source chunk pre-swizzled: cg = (lane&7)^(row&7)
  const int srow = lane >> 3;
  const int cg = (lane & 7) ^ srow;
  const char* aptr[4];
  const char* bptr[4];
#pragma unroll
  for (int i = 0; i < 4; ++i) {
    const int r = i * 32 + wid * 8 + srow;
    const int rr = (r < cnt_local) ? r : (cnt_local - 1);
    if (!is_g1) {
      const int tok = rowmap[off_e + loc_rt * BM + rr] >> 1;
      aptr[i] = (const char*)(hsb + (size_t)tok * H_DIM) + cg * 16;
    } else {
      aptr[i] = (const char*)(act + (size_t)(r_base + rr) * I_DIM) + cg * 16;
    }
    bptr[i] = (const char*)(wbase + (size_t)r * KD) + cg * 16;
  }
  unsigned short* dstA[4];
  unsigned short* dstB[4];
#pragma unroll
  for (int i = 0; i < 4; ++i) {
    dstA[i] = &As[(i * 32 + wid * 8) * BK];
    dstB[i] = &Bs[(i * 32 + wid * 8) * BK];
  }

  f32x4 acc[4][4];
#pragma unroll
  for (int m = 0; m < 4; ++m)
#pragma unroll
    for (int n = 0; n < 4; ++n) acc[m][n] = (f32x4){0.f, 0.f, 0.f, 0.f};

  const int wm = (wid >> 1) * 64;
  const int wn = (wid & 1) * 64;
  const int fr = lane & 15;
  const int fq = lane >> 4;
  const int sxor = fr & 7;

  for (int k0 = 0; k0 < KD; k0 += BK) {
    const int kb = k0 * 2;
#pragma unroll
    for (int i = 0; i < 4; ++i) gload16(aptr[i] + kb, dstA[i]);
#pragma unroll
    for (int i = 0; i < 4; ++i) gload16(bptr[i] + kb, dstB[i]);
    __syncthreads();   // drains vmcnt before s_barrier

#pragma unroll
    for (int kk = 0; kk < 2; ++kk) {
      bf16x8 af[4], bf[4];
#pragma unroll
      for (int m = 0; m < 4; ++m)
        af[m] = *reinterpret_cast<const bf16x8*>(
            &As[(wm + m * 16 + fr) * BK + ((kk * 4 + fq) ^ sxor) * 8]);
#pragma unroll
      for (int n = 0; n < 4; ++n)
        bf[n] = *reinterpret_cast<const bf16x8*>(
            &Bs[(wn + n * 16 + fr) * BK + ((kk * 4 + fq) ^ sxor) * 8]);
#pragma unroll
      for (int m = 0; m < 4; ++m)
#pragma unroll
        for (int n = 0; n < 4; ++n)
          acc[m][n] = __builtin_amdgcn_mfma_f32_16x16x32_bf16(af[m], bf[n], acc[m][n], 0, 0, 0);
    }
    __syncthreads();
  }

  // ---- epilogue ----
#pragma unroll
  for (int m = 0; m < 4; ++m) {
    const int row = wm + m * 16 + fq * 4;
#pragma unroll
    for (int n = 0; n < 4; ++n) {
      const int col = wn + n * 16 + fr;
#pragma unroll
      for (int r = 0; r < 4; ++r) {
        const int rw = row + r;
        if (rw < cnt_local) {
          const float x = acc[m][n][r];
          if (!is_g1) {
            const float s = x / (1.f + __expf(-x));   // silu
            act[(size_t)(r_base + rw) * I_DIM + n0 + col] = f2bf(s);
          } else {
            const int tok = s_pair[rw] >> 1;
            atomicAdd(out + (size_t)tok * H_DIM + n0 + col, x * s_w[rw]);
          }
        }
      }
    }
  }

  if (!is_g1) {   // publish this act tile (28 per rt)
    __threadfence();
    __syncthreads();
    if (th == 0) atomicAdd(&flags[rt], 1);
  }
}

// ---------------- launch ----------------
extern "C" void kernel_launch(void* const* d_in, const int* in_sizes, int n_in,
                              void* d_out, int out_size, void* d_ws, size_t ws_size,
                              hipStream_t stream) {
  const float* hs = (const float*)d_in[0];
  const float* gw = (const float*)d_in[1];
  const float* w1 = (const float*)d_in[2];
  const float* w2 = (const float*)d_in[3];
  float* out = (float*)d_out;

  char* ws = (char*)d_ws;
  const size_t WMAT = (size_t)E_NUM * I_DIM * H_DIM * 2;   // 58,720,256 B
  unsigned short* w1t = (unsigned short*)ws;                // [E][I][H] bf16
  unsigned short* w2t = (unsigned short*)(ws + WMAT);       // [E][H][I] bf16
  unsigned short* act = (unsigned short*)(ws + 2 * WMAT);   // [NPAIR][I] bf16
  unsigned short* hsb = (unsigned short*)(ws + 3 * WMAT);   // [T][H] bf16
  char* small = ws + 3 * WMAT + (size_t)T_TOK * H_DIM * 2;
  int* eid = (int*)small;                          // NPAIR
  float* wgt = (float*)(small + NPAIR * 4);        // NPAIR
  int* rowmap = (int*)(small + 2 * NPAIR * 4);     // NPAIR
  int* counts = (int*)(small + 3 * NPAIR * 4);     // 8
  int* fill = counts + 8;                          // 8
  int* flags = counts + 16;                        // 73 (ready[72] + w2t_cnt)

  hipMemsetAsync(counts, 0, (16 + 80) * sizeof(int), stream);
  hipMemsetAsync(d_out, 0, (size_t)T_TOK * H_DIM * sizeof(float), stream);

  prep1_kernel<<<256 + 3584, 256, 0, stream>>>(w1, hs, gw, w1t, hsb, eid, wgt, counts);
  scatter_kernel<<<NPAIR / 256, 256, 0, stream>>>(eid, counts, fill, rowmap);

  fused_moe_kernel<<<G0_NWG + WT_NB + G1_NWG, 256, 0, stream>>>(
      hsb, w1t, act, w2, w2t, out, counts, rowmap, wgt, flags);
}

// Round 19
// 257.155 us; speedup vs baseline: 4.7228x; 4.7228x over previous
//
#include <hip/hip_runtime.h>
#include <hip/hip_bf16.h>

// ---------------- problem constants (match setup_inputs) ----------------
#define T_TOK 4096
#define H_DIM 1024
#define E_NUM 8
#define I_DIM 3584
#define NPAIR (T_TOK * 2)   // top_k = 2
#define MAX_RT 72           // worst-case total row tiles: sum ceil(cnt_e/128) <= 64+7

#define BM 128
#define BN 128
#define BK 64
#define G0_NWG (MAX_RT * (I_DIM / BN))   // 2016 gemm0 blocks (252 octets)
#define WT_NB 3584                       // w2 transpose blocks (448 octets)

typedef __attribute__((ext_vector_type(8))) short bf16x8;
typedef __attribute__((ext_vector_type(4))) float f32x4;
typedef __attribute__((ext_vector_type(8))) unsigned short ushort8_t;
typedef __attribute__((ext_vector_type(4))) unsigned short ushort4_t;

// RNE fp32 -> bf16
__device__ __forceinline__ unsigned short f2bf(float x) {
  unsigned int u = __float_as_uint(x);
  unsigned int r = (u + 0x7FFFu + ((u >> 16) & 1u)) >> 16;
  return (unsigned short)r;
}

// async 16B global -> LDS (dest: wave-uniform base, HW adds lane*16)
__device__ __forceinline__ void gload16(const void* g, unsigned short* l) {
  __builtin_amdgcn_global_load_lds(
      (const __attribute__((address_space(1))) void*)g,
      (__attribute__((address_space(3))) void*)l, 16, 0, 0);
}

// ---------------- dual-tile transpose (2x 64-row passes, fused 256B writes) -
__device__ __forceinline__ void transpose_body2(const float* __restrict__ src,
                                                unsigned short* __restrict__ dst,
                                                int R, int C, int e, int c0, int r0,
                                                char* smem) {
  float (*tile)[65] = reinterpret_cast<float (*)[65]>(smem);
  const float* s = src + (size_t)e * R * C;
  unsigned short* d = dst + (size_t)e * R * C;
  const int th = threadIdx.x;
  const int tr = th >> 4;
  const int tc4 = (th & 15) * 4;
  const int wc = th >> 3;
  const int wr = (th & 7) * 8;
  ushort8_t oA[2];
#pragma unroll
  for (int it = 0; it < 4; ++it) {
    const int r = it * 16 + tr;
    float4 v = *reinterpret_cast<const float4*>(s + (size_t)(r0 + r) * C + c0 + tc4);
    tile[r][tc4] = v.x; tile[r][tc4 + 1] = v.y; tile[r][tc4 + 2] = v.z; tile[r][tc4 + 3] = v.w;
  }
  __syncthreads();
#pragma unroll
  for (int it = 0; it < 2; ++it) {
    const int c = it * 32 + wc;
#pragma unroll
    for (int j = 0; j < 8; ++j) oA[it][j] = f2bf(tile[wr + j][c]);
  }
  __syncthreads();
#pragma unroll
  for (int it = 0; it < 4; ++it) {
    const int r = it * 16 + tr;
    float4 v = *reinterpret_cast<const float4*>(s + (size_t)(r0 + 64 + r) * C + c0 + tc4);
    tile[r][tc4] = v.x; tile[r][tc4 + 1] = v.y; tile[r][tc4 + 2] = v.z; tile[r][tc4 + 3] = v.w;
  }
  __syncthreads();
#pragma unroll
  for (int it = 0; it < 2; ++it) {
    const int c = it * 32 + wc;
    ushort8_t oB;
#pragma unroll
    for (int j = 0; j < 8; ++j) oB[j] = f2bf(tile[wr + j][c]);
    *reinterpret_cast<ushort8_t*>(d + (size_t)(c0 + c) * R + r0 + wr) = oA[it];
    *reinterpret_cast<ushort8_t*>(d + (size_t)(c0 + c) * R + r0 + 64 + wr) = oB;
  }
}

__device__ __forceinline__ void router_body(const float* __restrict__ hs,
                                            const float* __restrict__ gw,
                                            unsigned short* __restrict__ hsb,
                                            int* __restrict__ eid, float* __restrict__ wgt,
                                            int* __restrict__ counts, int rbid, char* smem) {
  float* s_gw = reinterpret_cast<float*>(smem);          // 32 KB
  int* s_cnt = reinterpret_cast<int*>(smem + 32768);     // 32 B
  const int th = threadIdx.x;
  for (int u = th; u < 2048; u += 256) {
    const f32x4 v = *reinterpret_cast<const f32x4*>(gw + u * 4);
    *reinterpret_cast<f32x4*>(&s_gw[(u ^ ((u >> 3) & 7)) * 4]) = v;
  }
  if (th < E_NUM) s_cnt[th] = 0;
  __syncthreads();

  const int l = th & 63, w = th >> 6;
#pragma unroll 1
  for (int tt = 0; tt < 4; ++tt) {
    const int t = rbid * 16 + w * 4 + tt;
    const float* hrow = hs + (size_t)t * H_DIM;
    unsigned short* brow = hsb + (size_t)t * H_DIM;
    float acc[E_NUM];
#pragma unroll
    for (int e = 0; e < E_NUM; ++e) acc[e] = 0.f;
#pragma unroll
    for (int i = 0; i < 4; ++i) {
      const int h0 = i * 256 + l * 4;
      const f32x4 x = *reinterpret_cast<const f32x4*>(hrow + h0);
      ushort4_t o = { f2bf(x[0]), f2bf(x[1]), f2bf(x[2]), f2bf(x[3]) };
      *reinterpret_cast<ushort4_t*>(brow + h0) = o;
#pragma unroll
      for (int j = 0; j < 4; ++j) {
        const int h = h0 + j;
        const int p0 = (h * 2) ^ ((h >> 2) & 7);
        const f32x4 g0 = *reinterpret_cast<const f32x4*>(&s_gw[p0 * 4]);
        const f32x4 g1 = *reinterpret_cast<const f32x4*>(&s_gw[(p0 ^ 1) * 4]);
        acc[0] += x[j] * g0[0]; acc[1] += x[j] * g0[1];
        acc[2] += x[j] * g0[2]; acc[3] += x[j] * g0[3];
        acc[4] += x[j] * g1[0]; acc[5] += x[j] * g1[1];
        acc[6] += x[j] * g1[2]; acc[7] += x[j] * g1[3];
      }
    }
#pragma unroll
    for (int e = 0; e < E_NUM; ++e) {
#pragma unroll
      for (int off = 1; off < 64; off <<= 1) acc[e] += __shfl_xor(acc[e], off);
    }
    if (l == 0) {
      int i1 = 0;
#pragma unroll
      for (int e = 1; e < E_NUM; ++e) if (acc[e] > acc[i1]) i1 = e;
      int i2 = (i1 == 0) ? 1 : 0;
#pragma unroll
      for (int e = 0; e < E_NUM; ++e) if (e != i1 && acc[e] > acc[i2]) i2 = e;
      const float e2 = __expf(acc[i2] - acc[i1]);
      const float inv = 1.f / (1.f + e2);
      eid[t * 2] = i1;     wgt[t * 2] = inv;
      eid[t * 2 + 1] = i2; wgt[t * 2 + 1] = e2 * inv;
      atomicAdd(&s_cnt[i1], 1);
      atomicAdd(&s_cnt[i2], 1);
    }
  }
  __syncthreads();
  if (th < E_NUM && s_cnt[th] > 0) atomicAdd(&counts[th], s_cnt[th]);
}

// ---- kernel1: router (bids 0..255) + w1 dual-transpose (256..3839) --------
__global__ __launch_bounds__(256) void prep1_kernel(
    const float* __restrict__ w1, const float* __restrict__ hs,
    const float* __restrict__ gw,
    unsigned short* __restrict__ w1t, unsigned short* __restrict__ hsb,
    int* __restrict__ eid, float* __restrict__ wgt, int* __restrict__ counts) {
  __shared__ char smem[33024];
  const int bid = blockIdx.x;
  if (bid < 256) {
    router_body(hs, gw, hsb, eid, wgt, counts, bid, smem);
    return;
  }
  const int idx = bid - 256;     // w1: R=1024, C=3584; 56c x 8 row-pairs per e
  const int e = idx / 448, rem = idx % 448;
  transpose_body2(w1, w1t, H_DIM, I_DIM, e, (rem % 56) * 64, (rem / 56) * 128, smem);
}

// ---------------- scatter: block-local histogram + range reservation -------
__global__ void scatter_kernel(const int* __restrict__ eid, const int* __restrict__ counts,
                               int* __restrict__ fill, int* __restrict__ rowmap) {
  __shared__ int hist[E_NUM], base[E_NUM];
  const int th = threadIdx.x;
  const int p = blockIdx.x * 256 + th;
  if (th < E_NUM) hist[th] = 0;
  __syncthreads();
  const int e = eid[p];
  const int rloc = atomicAdd(&hist[e], 1);
  __syncthreads();
  if (th < E_NUM) base[th] = (hist[th] > 0) ? atomicAdd(&fill[th], hist[th]) : 0;
  __syncthreads();
  int off = 0;
#pragma unroll
  for (int i = 0; i < E_NUM; ++i) off += (i < e) ? counts[i] : 0;
  rowmap[off + base[e] + rloc] = p;
}

// ---- kernel2: gemm0 + w2 transpose, OCTET-INTERLEAVED -----------------------
// per 25 octets (200 bids): 9 octets gemm0 + 16 octets w2t, so the BW-bound
// transpose waves cohabit with latency-bound gemm0 waves across the WHOLE
// kernel window (not just the backfill tail). g0idx == bid (mod 8), so the
// XCD supertile mapping is exactly R17's.
__global__ __launch_bounds__(256, 4) void gemm0_w2t_kernel(
    const unsigned short* __restrict__ hsb, const unsigned short* __restrict__ w1t,
    unsigned short* __restrict__ act,
    const float* __restrict__ w2, unsigned short* __restrict__ w2t,
    const int* __restrict__ counts, const int* __restrict__ rowmap) {
  __shared__ char smem[(BM * BK + BN * BK) * 2];   // 32 KB
  const int bid = blockIdx.x;
  const int oct = bid >> 3, l8 = bid & 7;
  const int grp = oct / 25, pos = oct % 25;

  if (pos >= 9) {
    // w2 transpose: idx in [0, 3584)
    const int idx = (grp * 16 + (pos - 9)) * 8 + l8;
    const int e = idx / 448, rem = idx % 448;
    transpose_body2(w2, w2t, I_DIM, H_DIM, e, (rem % 16) * 64, (rem / 16) * 128, smem);
    return;
  }
  const int g0idx = (grp * 9 + pos) * 8 + l8;   // [0, 2016), g0idx%8 == bid%8

  unsigned short* As = reinterpret_cast<unsigned short*>(smem);
  unsigned short* Bs = As + BM * BK;

  // T1 bijective XCD swizzle + 9rt x 4ct supertile (A 2.3MB + B 1MB in L2)
  constexpr int CHUNK = G0_NWG / 8;   // 252
  const int wgid = (g0idx & 7) * CHUNK + (g0idx >> 3);
  const int l = wgid % CHUNK;
  const int sg = l / 36;
  const int q = l % 36;
  const int rt = (wgid / CHUNK) * 9 + q % 9;
  const int ct = sg * 4 + q / 9;

  // expert walk from counts (prefix on the fly)
  int e = -1, loc_rt = 0, off_e = 0, cnt = 0;
  {
    int acc_t = 0, off = 0;
#pragma unroll
    for (int ee = 0; ee < E_NUM; ++ee) {
      const int c = counts[ee];
      const int nt = (c + BM - 1) >> 7;
      if (e < 0 && rt < acc_t + nt) { e = ee; loc_rt = rt - acc_t; off_e = off; cnt = c; }
      acc_t += nt; off += c;
    }
  }
  if (e < 0) return;

  const int cnt_local = min(BM, cnt - loc_rt * BM);
  const int r_base = off_e + loc_rt * BM;
  const int th = threadIdx.x;
  const int lane = th & 63, wid = th >> 6;

  const int n0 = ct * BN;
  const unsigned short* wbase = w1t + (size_t)e * ((size_t)I_DIM * H_DIM) + (size_t)n0 * H_DIM;

  // staging: LDS dest linear; source chunk pre-swizzled: cg = (lane&7)^(row&7)
  const int srow = lane >> 3;
  const int cg = (lane & 7) ^ srow;
  const char* aptr[4];
  const char* bptr[4];
#pragma unroll
  for (int i = 0; i < 4; ++i) {
    const int r = i * 32 + wid * 8 + srow;
    const int rr = (r < cnt_local) ? r : (cnt_local - 1);
    const int tok = rowmap[off_e + loc_rt * BM + rr] >> 1;
    aptr[i] = (const char*)(hsb + (size_t)tok * H_DIM) + cg * 16;
    bptr[i] = (const char*)(wbase + (size_t)r * H_DIM) + cg * 16;
  }
  unsigned short* dstA[4];
  unsigned short* dstB[4];
#pragma unroll
  for (int i = 0; i < 4; ++i) {
    dstA[i] = &As[(i * 32 + wid * 8) * BK];
    dstB[i] = &Bs[(i * 32 + wid * 8) * BK];
  }

  f32x4 acc[4][4];
#pragma unroll
  for (int m = 0; m < 4; ++m)
#pragma unroll
    for (int n = 0; n < 4; ++n) acc[m][n] = (f32x4){0.f, 0.f, 0.f, 0.f};

  const int wm = (wid >> 1) * 64;
  const int wn = (wid & 1) * 64;
  const int fr = lane & 15;
  const int fq = lane >> 4;
  const int sxor = fr & 7;

  for (int k0 = 0; k0 < H_DIM; k0 += BK) {
    const int kb = k0 * 2;
#pragma unroll
    for (int i = 0; i < 4; ++i) gload16(aptr[i] + kb, dstA[i]);
#pragma unroll
    for (int i = 0; i < 4; ++i) gload16(bptr[i] + kb, dstB[i]);
    __syncthreads();

#pragma unroll
    for (int kk = 0; kk < 2; ++kk) {
      bf16x8 af[4], bf[4];
#pragma unroll
      for (int m = 0; m < 4; ++m)
        af[m] = *reinterpret_cast<const bf16x8*>(
            &As[(wm + m * 16 + fr) * BK + ((kk * 4 + fq) ^ sxor) * 8]);
#pragma unroll
      for (int n = 0; n < 4; ++n)
        bf[n] = *reinterpret_cast<const bf16x8*>(
            &Bs[(wn + n * 16 + fr) * BK + ((kk * 4 + fq) ^ sxor) * 8]);
#pragma unroll
      for (int m = 0; m < 4; ++m)
#pragma unroll
        for (int n = 0; n < 4; ++n)
          acc[m][n] = __builtin_amdgcn_mfma_f32_16x16x32_bf16(af[m], bf[n], acc[m][n], 0, 0, 0);
    }
    __syncthreads();
  }

  // ---- epilogue: silu -> act bf16
#pragma unroll
  for (int m = 0; m < 4; ++m) {
    const int row = wm + m * 16 + fq * 4;
#pragma unroll
    for (int n = 0; n < 4; ++n) {
      const int col = wn + n * 16 + fr;
#pragma unroll
      for (int r = 0; r < 4; ++r) {
        const int rw = row + r;
        if (rw < cnt_local) {
          const float x = acc[m][n][r];
          const float s = x / (1.f + __expf(-x));
          act[(size_t)(r_base + rw) * I_DIM + n0 + col] = f2bf(s);
        }
      }
    }
  }
}

// ---------------- gemm1 (128x128, band-of-2rt chunks, atomicAdd -> out) ----
__launch_bounds__(256, 4)
__global__ void moe_gemm1(const unsigned short* __restrict__ w2t,
                          const unsigned short* __restrict__ act_in,
                          float* __restrict__ out,
                          const int* __restrict__ counts,
                          const int* __restrict__ rowmap,
                          const float* __restrict__ wgt) {
  constexpr int NCT = H_DIM / BN;            // 8
  constexpr int NWG = MAX_RT * NCT;          // 576
  constexpr int CHUNK = NWG / 8;             // 72

  __shared__ unsigned short As[BM * BK];
  __shared__ unsigned short Bs[BN * BK];
  __shared__ int s_pair[BM];
  __shared__ float s_w[BM];

  // T1 bijective XCD swizzle; band of 2rt x 8ct within each 72-wgid chunk
  const int bid = blockIdx.x;
  const int wgid = (bid & 7) * CHUNK + (bid >> 3);
  int rt, ct;
  {
    const int c9 = (wgid / CHUNK) * 9;
    const int l = wgid % CHUNK;
    if (l < 64) {
      const int band = l >> 4, inner = l & 15;
      rt = c9 + band * 2 + (inner & 1);
      ct = inner >> 1;
    } else {
      rt = c9 + 8;
      ct = l - 64;
    }
  }

  // expert walk from counts (prefix on the fly)
  int e = -1, loc_rt = 0, off_e = 0, cnt = 0;
  {
    int acc_t = 0, off = 0;
#pragma unroll
    for (int ee = 0; ee < E_NUM; ++ee) {
      const int c = counts[ee];
      const int nt = (c + BM - 1) >> 7;
      if (e < 0 && rt < acc_t + nt) { e = ee; loc_rt = rt - acc_t; off_e = off; cnt = c; }
      acc_t += nt; off += c;
    }
  }
  if (e < 0) return;

  const int cnt_local = min(BM, cnt - loc_rt * BM);
  const int r_base = off_e + loc_rt * BM;
  const int th = threadIdx.x;
  const int lane = th & 63, wid = th >> 6;

  if (th < BM) {
    int r = loc_rt * BM + th;
    if (r >= cnt) r = cnt - 1;
    const int p = rowmap[off_e + r];
    s_pair[th] = p;
    s_w[th] = wgt[p];
  }

  const int n0 = ct * BN;
  const unsigned short* wbase = w2t + (size_t)e * ((size_t)I_DIM * H_DIM) + (size_t)n0 * I_DIM;

  const int srow = lane >> 3;
  const int cg = (lane & 7) ^ srow;
  const char* aptr[4];
  const char* bptr[4];
#pragma unroll
  for (int i = 0; i < 4; ++i) {
    const int r = i * 32 + wid * 8 + srow;
    const int rr = (r < cnt_local) ? r : (cnt_local - 1);
    aptr[i] = (const char*)(act_in + (size_t)(r_base + rr) * I_DIM) + cg * 16;
    bptr[i] = (const char*)(wbase + (size_t)r * I_DIM) + cg * 16;
  }
  unsigned short* dstA[4];
  unsigned short* dstB[4];
#pragma unroll
  for (int i = 0; i < 4; ++i) {
    dstA[i] = &As[(i * 32 + wid * 8) * BK];
    dstB[i] = &Bs[(i * 32 + wid * 8) * BK];
  }

  f32x4 acc[4][4];
#pragma unroll
  for (int m = 0; m < 4; ++m)
#pragma unroll
    for (int n = 0; n < 4; ++n) acc[m][n] = (f32x4){0.f, 0.f, 0.f, 0.f};

  const int wm = (wid >> 1) * 64;
  const int wn = (wid & 1) * 64;
  const int fr = lane & 15;
  const int fq = lane >> 4;
  const int sxor = fr & 7;

  for (int k0 = 0; k0 < I_DIM; k0 += BK) {
    const int kb = k0 * 2;
#pragma unroll
    for (int i = 0; i < 4; ++i) gload16(aptr[i] + kb, dstA[i]);
#pragma unroll
    for (int i = 0; i < 4; ++i) gload16(bptr[i] + kb, dstB[i]);
    __syncthreads();

#pragma unroll
    for (int kk = 0; kk < 2; ++kk) {
      bf16x8 af[4], bf[4];
#pragma unroll
      for (int m = 0; m < 4; ++m)
        af[m] = *reinterpret_cast<const bf16x8*>(
            &As[(wm + m * 16 + fr) * BK + ((kk * 4 + fq) ^ sxor) * 8]);
#pragma unroll
      for (int n = 0; n < 4; ++n)
        bf[n] = *reinterpret_cast<const bf16x8*>(
            &Bs[(wn + n * 16 + fr) * BK + ((kk * 4 + fq) ^ sxor) * 8]);
#pragma unroll
      for (int m = 0; m < 4; ++m)
#pragma unroll
        for (int n = 0; n < 4; ++n)
          acc[m][n] = __builtin_amdgcn_mfma_f32_16x16x32_bf16(af[m], bf[n], acc[m][n], 0, 0, 0);
    }
    __syncthreads();
  }

  // ---- epilogue: weighted atomic add into out (2 contributions/element)
#pragma unroll
  for (int m = 0; m < 4; ++m) {
    const int row = wm + m * 16 + fq * 4;
#pragma unroll
    for (int n = 0; n < 4; ++n) {
      const int col = wn + n * 16 + fr;
#pragma unroll
      for (int r = 0; r < 4; ++r) {
        const int rw = row + r;
        if (rw < cnt_local) {
          const int tok = s_pair[rw] >> 1;
          atomicAdd(out + (size_t)tok * H_DIM + n0 + col, acc[m][n][r] * s_w[rw]);
        }
      }
    }
  }
}

// ---------------- launch ----------------
extern "C" void kernel_launch(void* const* d_in, const int* in_sizes, int n_in,
                              void* d_out, int out_size, void* d_ws, size_t ws_size,
                              hipStream_t stream) {
  const float* hs = (const float*)d_in[0];
  const float* gw = (const float*)d_in[1];
  const float* w1 = (const float*)d_in[2];
  const float* w2 = (const float*)d_in[3];
  float* out = (float*)d_out;

  char* ws = (char*)d_ws;
  const size_t WMAT = (size_t)E_NUM * I_DIM * H_DIM * 2;   // 58,720,256 B
  unsigned short* w1t = (unsigned short*)ws;                // [E][I][H] bf16
  unsigned short* w2t = (unsigned short*)(ws + WMAT);       // [E][H][I] bf16
  unsigned short* act = (unsigned short*)(ws + 2 * WMAT);   // [NPAIR][I] bf16
  unsigned short* hsb = (unsigned short*)(ws + 3 * WMAT);   // [T][H] bf16
  char* small = ws + 3 * WMAT + (size_t)T_TOK * H_DIM * 2;
  int* eid = (int*)small;                          // NPAIR
  float* wgt = (float*)(small + NPAIR * 4);        // NPAIR
  int* rowmap = (int*)(small + 2 * NPAIR * 4);     // NPAIR
  int* counts = (int*)(small + 3 * NPAIR * 4);     // 8
  int* fill = counts + 8;                          // 8

  hipMemsetAsync(counts, 0, 16 * sizeof(int), stream);
  hipMemsetAsync(d_out, 0, (size_t)T_TOK * H_DIM * sizeof(float), stream);

  prep1_kernel<<<256 + 3584, 256, 0, stream>>>(w1, hs, gw, w1t, hsb, eid, wgt, counts);
  scatter_kernel<<<NPAIR / 256, 256, 0, stream>>>(eid, counts, fill, rowmap);

  gemm0_w2t_kernel<<<G0_NWG + WT_NB, 256, 0, stream>>>(
      hsb, w1t, act, w2, w2t, counts, rowmap);
  moe_gemm1<<<MAX_RT * (H_DIM / BN), 256, 0, stream>>>(
      w2t, act, out, counts, rowmap, wgt);
}

// Round 20
// 256.979 us; speedup vs baseline: 4.7260x; 1.0007x over previous
//
#include <hip/hip_runtime.h>
#include <hip/hip_bf16.h>

// ---------------- problem constants (match setup_inputs) ----------------
#define T_TOK 4096
#define H_DIM 1024
#define E_NUM 8
#define I_DIM 3584
#define NPAIR (T_TOK * 2)   // top_k = 2
#define MAX_RT 72           // worst-case total row tiles: sum ceil(cnt_e/128) <= 64+7

#define BM 128
#define BN 128
#define BK 64
#define G0_NWG (MAX_RT * (I_DIM / BN))   // 2016 gemm0 blocks
#define WT_NB 3584                       // w2 dual-tile transpose blocks

typedef __attribute__((ext_vector_type(8))) short bf16x8;
typedef __attribute__((ext_vector_type(4))) float f32x4;
typedef __attribute__((ext_vector_type(8))) unsigned short ushort8_t;
typedef __attribute__((ext_vector_type(4))) unsigned short ushort4_t;

// RNE fp32 -> bf16
__device__ __forceinline__ unsigned short f2bf(float x) {
  unsigned int u = __float_as_uint(x);
  unsigned int r = (u + 0x7FFFu + ((u >> 16) & 1u)) >> 16;
  return (unsigned short)r;
}

// async 16B global -> LDS (dest: wave-uniform base, HW adds lane*16)
__device__ __forceinline__ void gload16(const void* g, unsigned short* l) {
  __builtin_amdgcn_global_load_lds(
      (const __attribute__((address_space(1))) void*)g,
      (__attribute__((address_space(3))) void*)l, 16, 0, 0);
}

// ---------------- dual-tile transpose (2x 64-row passes, fused 256B writes) -
__device__ __forceinline__ void transpose_body2(const float* __restrict__ src,
                                                unsigned short* __restrict__ dst,
                                                int R, int C, int e, int c0, int r0,
                                                char* smem) {
  float (*tile)[65] = reinterpret_cast<float (*)[65]>(smem);
  const float* s = src + (size_t)e * R * C;
  unsigned short* d = dst + (size_t)e * R * C;
  const int th = threadIdx.x;
  const int tr = th >> 4;
  const int tc4 = (th & 15) * 4;
  const int wc = th >> 3;
  const int wr = (th & 7) * 8;
  ushort8_t oA[2];
#pragma unroll
  for (int it = 0; it < 4; ++it) {
    const int r = it * 16 + tr;
    float4 v = *reinterpret_cast<const float4*>(s + (size_t)(r0 + r) * C + c0 + tc4);
    tile[r][tc4] = v.x; tile[r][tc4 + 1] = v.y; tile[r][tc4 + 2] = v.z; tile[r][tc4 + 3] = v.w;
  }
  __syncthreads();
#pragma unroll
  for (int it = 0; it < 2; ++it) {
    const int c = it * 32 + wc;
#pragma unroll
    for (int j = 0; j < 8; ++j) oA[it][j] = f2bf(tile[wr + j][c]);
  }
  __syncthreads();
#pragma unroll
  for (int it = 0; it < 4; ++it) {
    const int r = it * 16 + tr;
    float4 v = *reinterpret_cast<const float4*>(s + (size_t)(r0 + 64 + r) * C + c0 + tc4);
    tile[r][tc4] = v.x; tile[r][tc4 + 1] = v.y; tile[r][tc4 + 2] = v.z; tile[r][tc4 + 3] = v.w;
  }
  __syncthreads();
#pragma unroll
  for (int it = 0; it < 2; ++it) {
    const int c = it * 32 + wc;
    ushort8_t oB;
#pragma unroll
    for (int j = 0; j < 8; ++j) oB[j] = f2bf(tile[wr + j][c]);
    *reinterpret_cast<ushort8_t*>(d + (size_t)(c0 + c) * R + r0 + wr) = oA[it];
    *reinterpret_cast<ushort8_t*>(d + (size_t)(c0 + c) * R + r0 + 64 + wr) = oB;
  }
}

__device__ __forceinline__ void router_body(const float* __restrict__ hs,
                                            const float* __restrict__ gw,
                                            unsigned short* __restrict__ hsb,
                                            int* __restrict__ eid, float* __restrict__ wgt,
                                            int* __restrict__ counts, int rbid, char* smem) {
  float* s_gw = reinterpret_cast<float*>(smem);          // 32 KB
  int* s_cnt = reinterpret_cast<int*>(smem + 32768);     // 32 B
  const int th = threadIdx.x;
  for (int u = th; u < 2048; u += 256) {
    const f32x4 v = *reinterpret_cast<const f32x4*>(gw + u * 4);
    *reinterpret_cast<f32x4*>(&s_gw[(u ^ ((u >> 3) & 7)) * 4]) = v;
  }
  if (th < E_NUM) s_cnt[th] = 0;
  __syncthreads();

  const int l = th & 63, w = th >> 6;
#pragma unroll 1
  for (int tt = 0; tt < 4; ++tt) {
    const int t = rbid * 16 + w * 4 + tt;
    const float* hrow = hs + (size_t)t * H_DIM;
    unsigned short* brow = hsb + (size_t)t * H_DIM;
    float acc[E_NUM];
#pragma unroll
    for (int e = 0; e < E_NUM; ++e) acc[e] = 0.f;
#pragma unroll
    for (int i = 0; i < 4; ++i) {
      const int h0 = i * 256 + l * 4;
      const f32x4 x = *reinterpret_cast<const f32x4*>(hrow + h0);
      ushort4_t o = { f2bf(x[0]), f2bf(x[1]), f2bf(x[2]), f2bf(x[3]) };
      *reinterpret_cast<ushort4_t*>(brow + h0) = o;
#pragma unroll
      for (int j = 0; j < 4; ++j) {
        const int h = h0 + j;
        const int p0 = (h * 2) ^ ((h >> 2) & 7);
        const f32x4 g0 = *reinterpret_cast<const f32x4*>(&s_gw[p0 * 4]);
        const f32x4 g1 = *reinterpret_cast<const f32x4*>(&s_gw[(p0 ^ 1) * 4]);
        acc[0] += x[j] * g0[0]; acc[1] += x[j] * g0[1];
        acc[2] += x[j] * g0[2]; acc[3] += x[j] * g0[3];
        acc[4] += x[j] * g1[0]; acc[5] += x[j] * g1[1];
        acc[6] += x[j] * g1[2]; acc[7] += x[j] * g1[3];
      }
    }
#pragma unroll
    for (int e = 0; e < E_NUM; ++e) {
#pragma unroll
      for (int off = 1; off < 64; off <<= 1) acc[e] += __shfl_xor(acc[e], off);
    }
    if (l == 0) {
      int i1 = 0;
#pragma unroll
      for (int e = 1; e < E_NUM; ++e) if (acc[e] > acc[i1]) i1 = e;
      int i2 = (i1 == 0) ? 1 : 0;
#pragma unroll
      for (int e = 0; e < E_NUM; ++e) if (e != i1 && acc[e] > acc[i2]) i2 = e;
      const float e2 = __expf(acc[i2] - acc[i1]);
      const float inv = 1.f / (1.f + e2);
      eid[t * 2] = i1;     wgt[t * 2] = inv;
      eid[t * 2 + 1] = i2; wgt[t * 2 + 1] = e2 * inv;
      atomicAdd(&s_cnt[i1], 1);
      atomicAdd(&s_cnt[i2], 1);
    }
  }
  __syncthreads();
  if (th < E_NUM && s_cnt[th] > 0) atomicAdd(&counts[th], s_cnt[th]);
}

// ---- kernel1: router (bids 0..255) + w1 dual-transpose (256..3839) --------
__global__ __launch_bounds__(256) void prep1_kernel(
    const float* __restrict__ w1, const float* __restrict__ hs,
    const float* __restrict__ gw,
    unsigned short* __restrict__ w1t, unsigned short* __restrict__ hsb,
    int* __restrict__ eid, float* __restrict__ wgt, int* __restrict__ counts) {
  __shared__ char smem[33024];
  const int bid = blockIdx.x;
  if (bid < 256) {
    router_body(hs, gw, hsb, eid, wgt, counts, bid, smem);
    return;
  }
  const int idx = bid - 256;     // w1: R=1024, C=3584; 56c x 8 row-pairs per e
  const int e = idx / 448, rem = idx % 448;
  transpose_body2(w1, w1t, H_DIM, I_DIM, e, (rem % 56) * 64, (rem / 56) * 128, smem);
}

// ---------------- scatter: block-local histogram + range reservation -------
__global__ void scatter_kernel(const int* __restrict__ eid, const int* __restrict__ counts,
                               int* __restrict__ fill, int* __restrict__ rowmap) {
  __shared__ int hist[E_NUM], base[E_NUM];
  const int th = threadIdx.x;
  const int p = blockIdx.x * 256 + th;
  if (th < E_NUM) hist[th] = 0;
  __syncthreads();
  const int e = eid[p];
  const int rloc = atomicAdd(&hist[e], 1);
  __syncthreads();
  if (th < E_NUM) base[th] = (hist[th] > 0) ? atomicAdd(&fill[th], hist[th]) : 0;
  __syncthreads();
  int off = 0;
#pragma unroll
  for (int i = 0; i < E_NUM; ++i) off += (i < e) ? counts[i] : 0;
  rowmap[off + base[e] + rloc] = p;
}

// ---- kernel2: gemm0 (bids 0..2015, supertiled) + w2 dual-transpose --------
// R17 concatenated layout (gemm0 first, w2t backfills the drain tail).
__global__ __launch_bounds__(256, 4) void gemm0_w2t_kernel(
    const unsigned short* __restrict__ hsb, const unsigned short* __restrict__ w1t,
    unsigned short* __restrict__ act,
    const float* __restrict__ w2, unsigned short* __restrict__ w2t,
    const int* __restrict__ counts, const int* __restrict__ rowmap) {
  __shared__ char smem[(BM * BK + BN * BK) * 2];   // 32 KB
  const int bid = blockIdx.x;
  if (bid >= G0_NWG) {
    const int idx = bid - G0_NWG;  // w2: R=3584, C=1024; 16c x 28 row-pairs/e
    const int e = idx / 448, rem = idx % 448;
    transpose_body2(w2, w2t, I_DIM, H_DIM, e, (rem % 16) * 64, (rem / 16) * 128, smem);
    return;
  }
  unsigned short* As = reinterpret_cast<unsigned short*>(smem);
  unsigned short* Bs = As + BM * BK;

  // T1 bijective XCD swizzle + 9rt x 4ct supertile (A 2.3MB + B 1MB in L2)
  constexpr int CHUNK = G0_NWG / 8;   // 252
  const int wgid = (bid & 7) * CHUNK + (bid >> 3);
  const int l = wgid % CHUNK;
  const int sg = l / 36;
  const int q = l % 36;
  const int rt = (wgid / CHUNK) * 9 + q % 9;
  const int ct = sg * 4 + q / 9;

  // expert walk from counts (prefix on the fly)
  int e = -1, loc_rt = 0, off_e = 0, cnt = 0;
  {
    int acc_t = 0, off = 0;
#pragma unroll
    for (int ee = 0; ee < E_NUM; ++ee) {
      const int c = counts[ee];
      const int nt = (c + BM - 1) >> 7;
      if (e < 0 && rt < acc_t + nt) { e = ee; loc_rt = rt - acc_t; off_e = off; cnt = c; }
      acc_t += nt; off += c;
    }
  }
  if (e < 0) return;

  const int cnt_local = min(BM, cnt - loc_rt * BM);
  const int r_base = off_e + loc_rt * BM;
  const int th = threadIdx.x;
  const int lane = th & 63, wid = th >> 6;

  const int n0 = ct * BN;
  const unsigned short* wbase = w1t + (size_t)e * ((size_t)I_DIM * H_DIM) + (size_t)n0 * H_DIM;

  // staging: LDS dest linear; source chunk pre-swizzled: cg = (lane&7)^(row&7)
  const int srow = lane >> 3;
  const int cg = (lane & 7) ^ srow;
  const char* aptr[4];
  const char* bptr[4];
#pragma unroll
  for (int i = 0; i < 4; ++i) {
    const int r = i * 32 + wid * 8 + srow;
    const int rr = (r < cnt_local) ? r : (cnt_local - 1);
    const int tok = rowmap[off_e + loc_rt * BM + rr] >> 1;
    aptr[i] = (const char*)(hsb + (size_t)tok * H_DIM) + cg * 16;
    bptr[i] = (const char*)(wbase + (size_t)r * H_DIM) + cg * 16;
  }
  unsigned short* dstA[4];
  unsigned short* dstB[4];
#pragma unroll
  for (int i = 0; i < 4; ++i) {
    dstA[i] = &As[(i * 32 + wid * 8) * BK];   // wave-uniform
    dstB[i] = &Bs[(i * 32 + wid * 8) * BK];
  }

  f32x4 acc[4][4];
#pragma unroll
  for (int m = 0; m < 4; ++m)
#pragma unroll
    for (int n = 0; n < 4; ++n) acc[m][n] = (f32x4){0.f, 0.f, 0.f, 0.f};

  const int wm = (wid >> 1) * 64;
  const int wn = (wid & 1) * 64;
  const int fr = lane & 15;
  const int fq = lane >> 4;
  const int sxor = fr & 7;

  for (int k0 = 0; k0 < H_DIM; k0 += BK) {
    const int kb = k0 * 2;
#pragma unroll
    for (int i = 0; i < 4; ++i) gload16(aptr[i] + kb, dstA[i]);
#pragma unroll
    for (int i = 0; i < 4; ++i) gload16(bptr[i] + kb, dstB[i]);
    __syncthreads();   // drains vmcnt before s_barrier

#pragma unroll
    for (int kk = 0; kk < 2; ++kk) {
      bf16x8 af[4], bf[4];
#pragma unroll
      for (int m = 0; m < 4; ++m)
        af[m] = *reinterpret_cast<const bf16x8*>(
            &As[(wm + m * 16 + fr) * BK + ((kk * 4 + fq) ^ sxor) * 8]);
#pragma unroll
      for (int n = 0; n < 4; ++n)
        bf[n] = *reinterpret_cast<const bf16x8*>(
            &Bs[(wn + n * 16 + fr) * BK + ((kk * 4 + fq) ^ sxor) * 8]);
#pragma unroll
      for (int m = 0; m < 4; ++m)
#pragma unroll
        for (int n = 0; n < 4; ++n)
          acc[m][n] = __builtin_amdgcn_mfma_f32_16x16x32_bf16(af[m], bf[n], acc[m][n], 0, 0, 0);
    }
    __syncthreads();
  }

  // ---- epilogue: silu -> act bf16
#pragma unroll
  for (int m = 0; m < 4; ++m) {
    const int row = wm + m * 16 + fq * 4;
#pragma unroll
    for (int n = 0; n < 4; ++n) {
      const int col = wn + n * 16 + fr;
#pragma unroll
      for (int r = 0; r < 4; ++r) {
        const int rw = row + r;
        if (rw < cnt_local) {
          const float x = acc[m][n][r];
          const float s = x / (1.f + __expf(-x));
          act[(size_t)(r_base + rw) * I_DIM + n0 + col] = f2bf(s);
        }
      }
    }
  }
}

// ---------------- gemm1 (128x128, band-of-2rt chunks, atomicAdd -> out) ----
__launch_bounds__(256, 4)
__global__ void moe_gemm1(const unsigned short* __restrict__ w2t,
                          const unsigned short* __restrict__ act_in,
                          float* __restrict__ out,
                          const int* __restrict__ counts,
                          const int* __restrict__ rowmap,
                          const float* __restrict__ wgt) {
  constexpr int NCT = H_DIM / BN;            // 8
  constexpr int NWG = MAX_RT * NCT;          // 576
  constexpr int CHUNK = NWG / 8;             // 72

  __shared__ unsigned short As[BM * BK];
  __shared__ unsigned short Bs[BN * BK];
  __shared__ int s_pair[BM];
  __shared__ float s_w[BM];

  // T1 bijective XCD swizzle; band of 2rt x 8ct within each 72-wgid chunk
  const int bid = blockIdx.x;
  const int wgid = (bid & 7) * CHUNK + (bid >> 3);
  int rt, ct;
  {
    const int c9 = (wgid / CHUNK) * 9;
    const int l = wgid % CHUNK;
    if (l < 64) {
      const int band = l >> 4, inner = l & 15;
      rt = c9 + band * 2 + (inner & 1);
      ct = inner >> 1;
    } else {
      rt = c9 + 8;
      ct = l - 64;
    }
  }

  // expert walk from counts (prefix on the fly)
  int e = -1, loc_rt = 0, off_e = 0, cnt = 0;
  {
    int acc_t = 0, off = 0;
#pragma unroll
    for (int ee = 0; ee < E_NUM; ++ee) {
      const int c = counts[ee];
      const int nt = (c + BM - 1) >> 7;
      if (e < 0 && rt < acc_t + nt) { e = ee; loc_rt = rt - acc_t; off_e = off; cnt = c; }
      acc_t += nt; off += c;
    }
  }
  if (e < 0) return;

  const int cnt_local = min(BM, cnt - loc_rt * BM);
  const int r_base = off_e + loc_rt * BM;
  const int th = threadIdx.x;
  const int lane = th & 63, wid = th >> 6;

  if (th < BM) {
    int r = loc_rt * BM + th;
    if (r >= cnt) r = cnt - 1;
    const int p = rowmap[off_e + r];
    s_pair[th] = p;
    s_w[th] = wgt[p];
  }

  const int n0 = ct * BN;
  const unsigned short* wbase = w2t + (size_t)e * ((size_t)I_DIM * H_DIM) + (size_t)n0 * I_DIM;

  const int srow = lane >> 3;
  const int cg = (lane & 7) ^ srow;
  const char* aptr[4];
  const char* bptr[4];
#pragma unroll
  for (int i = 0; i < 4; ++i) {
    const int r = i * 32 + wid * 8 + srow;
    const int rr = (r < cnt_local) ? r : (cnt_local - 1);
    aptr[i] = (const char*)(act_in + (size_t)(r_base + rr) * I_DIM) + cg * 16;
    bptr[i] = (const char*)(wbase + (size_t)r * I_DIM) + cg * 16;
  }
  unsigned short* dstA[4];
  unsigned short* dstB[4];
#pragma unroll
  for (int i = 0; i < 4; ++i) {
    dstA[i] = &As[(i * 32 + wid * 8) * BK];
    dstB[i] = &Bs[(i * 32 + wid * 8) * BK];
  }

  f32x4 acc[4][4];
#pragma unroll
  for (int m = 0; m < 4; ++m)
#pragma unroll
    for (int n = 0; n < 4; ++n) acc[m][n] = (f32x4){0.f, 0.f, 0.f, 0.f};

  const int wm = (wid >> 1) * 64;
  const int wn = (wid & 1) * 64;
  const int fr = lane & 15;
  const int fq = lane >> 4;
  const int sxor = fr & 7;

  for (int k0 = 0; k0 < I_DIM; k0 += BK) {
    const int kb = k0 * 2;
#pragma unroll
    for (int i = 0; i < 4; ++i) gload16(aptr[i] + kb, dstA[i]);
#pragma unroll
    for (int i = 0; i < 4; ++i) gload16(bptr[i] + kb, dstB[i]);
    __syncthreads();

#pragma unroll
    for (int kk = 0; kk < 2; ++kk) {
      bf16x8 af[4], bf[4];
#pragma unroll
      for (int m = 0; m < 4; ++m)
        af[m] = *reinterpret_cast<const bf16x8*>(
            &As[(wm + m * 16 + fr) * BK + ((kk * 4 + fq) ^ sxor) * 8]);
#pragma unroll
      for (int n = 0; n < 4; ++n)
        bf[n] = *reinterpret_cast<const bf16x8*>(
            &Bs[(wn + n * 16 + fr) * BK + ((kk * 4 + fq) ^ sxor) * 8]);
#pragma unroll
      for (int m = 0; m < 4; ++m)
#pragma unroll
        for (int n = 0; n < 4; ++n)
          acc[m][n] = __builtin_amdgcn_mfma_f32_16x16x32_bf16(af[m], bf[n], acc[m][n], 0, 0, 0);
    }
    __syncthreads();
  }

  // ---- epilogue: weighted atomic add into out (2 contributions/element)
#pragma unroll
  for (int m = 0; m < 4; ++m) {
    const int row = wm + m * 16 + fq * 4;
#pragma unroll
    for (int n = 0; n < 4; ++n) {
      const int col = wn + n * 16 + fr;
#pragma unroll
      for (int r = 0; r < 4; ++r) {
        const int rw = row + r;
        if (rw < cnt_local) {
          const int tok = s_pair[rw] >> 1;
          atomicAdd(out + (size_t)tok * H_DIM + n0 + col, acc[m][n][r] * s_w[rw]);
        }
      }
    }
  }
}

// ---------------- launch ----------------
extern "C" void kernel_launch(void* const* d_in, const int* in_sizes, int n_in,
                              void* d_out, int out_size, void* d_ws, size_t ws_size,
                              hipStream_t stream) {
  const float* hs = (const float*)d_in[0];
  const float* gw = (const float*)d_in[1];
  const float* w1 = (const float*)d_in[2];
  const float* w2 = (const float*)d_in[3];
  float* out = (float*)d_out;

  char* ws = (char*)d_ws;
  const size_t WMAT = (size_t)E_NUM * I_DIM * H_DIM * 2;   // 58,720,256 B
  unsigned short* w1t = (unsigned short*)ws;                // [E][I][H] bf16
  unsigned short* w2t = (unsigned short*)(ws + WMAT);       // [E][H][I] bf16
  unsigned short* act = (unsigned short*)(ws + 2 * WMAT);   // [NPAIR][I] bf16
  unsigned short* hsb = (unsigned short*)(ws + 3 * WMAT);   // [T][H] bf16
  char* small = ws + 3 * WMAT + (size_t)T_TOK * H_DIM * 2;
  int* eid = (int*)small;                          // NPAIR
  float* wgt = (float*)(small + NPAIR * 4);        // NPAIR
  int* rowmap = (int*)(small + 2 * NPAIR * 4);     // NPAIR
  int* counts = (int*)(small + 3 * NPAIR * 4);     // 8
  int* fill = counts + 8;                          // 8

  hipMemsetAsync(counts, 0, 16 * sizeof(int), stream);
  hipMemsetAsync(d_out, 0, (size_t)T_TOK * H_DIM * sizeof(float), stream);

  prep1_kernel<<<256 + 3584, 256, 0, stream>>>(w1, hs, gw, w1t, hsb, eid, wgt, counts);
  scatter_kernel<<<NPAIR / 256, 256, 0, stream>>>(eid, counts, fill, rowmap);

  gemm0_w2t_kernel<<<G0_NWG + WT_NB, 256, 0, stream>>>(
      hsb, w1t, act, w2, w2t, counts, rowmap);
  moe_gemm1<<<MAX_RT * (H_DIM / BN), 256, 0, stream>>>(
      w2t, act, out, counts, rowmap, wgt);
}

// Round 21
// 244.949 us; speedup vs baseline: 4.9581x; 1.0491x over previous
//
#include <hip/hip_runtime.h>
#include <hip/hip_bf16.h>

// ---------------- problem constants (match setup_inputs) ----------------
#define T_TOK 4096
#define H_DIM 1024
#define E_NUM 8
#define I_DIM 3584
#define NPAIR (T_TOK * 2)   // top_k = 2
#define MAX_RT 72           // worst-case total row tiles: sum ceil(cnt_e/128) <= 64+7

#define BM 128
#define BN 128
#define BK 64
#define G0_NWG (MAX_RT * (I_DIM / BN))   // 2016 gemm0 blocks
#define WT_NB 3584                       // dual-tile transpose blocks per matrix

typedef __attribute__((ext_vector_type(8))) short bf16x8;
typedef __attribute__((ext_vector_type(4))) float f32x4;
typedef __attribute__((ext_vector_type(8))) unsigned short ushort8_t;
typedef __attribute__((ext_vector_type(4))) unsigned short ushort4_t;

// RNE fp32 -> bf16
__device__ __forceinline__ unsigned short f2bf(float x) {
  unsigned int u = __float_as_uint(x);
  unsigned int r = (u + 0x7FFFu + ((u >> 16) & 1u)) >> 16;
  return (unsigned short)r;
}

// async 16B global -> LDS (dest: wave-uniform base, HW adds lane*16)
__device__ __forceinline__ void gload16(const void* g, unsigned short* l) {
  __builtin_amdgcn_global_load_lds(
      (const __attribute__((address_space(1))) void*)g,
      (__attribute__((address_space(3))) void*)l, 16, 0, 0);
}

// ---------------- dual-tile transpose (2x 64-row passes, fused 256B writes) -
__device__ __forceinline__ void transpose_body2(const float* __restrict__ src,
                                                unsigned short* __restrict__ dst,
                                                int R, int C, int e, int c0, int r0,
                                                char* smem) {
  float (*tile)[65] = reinterpret_cast<float (*)[65]>(smem);
  const float* s = src + (size_t)e * R * C;
  unsigned short* d = dst + (size_t)e * R * C;
  const int th = threadIdx.x;
  const int tr = th >> 4;
  const int tc4 = (th & 15) * 4;
  const int wc = th >> 3;
  const int wr = (th & 7) * 8;
  ushort8_t oA[2];
#pragma unroll
  for (int it = 0; it < 4; ++it) {
    const int r = it * 16 + tr;
    float4 v = *reinterpret_cast<const float4*>(s + (size_t)(r0 + r) * C + c0 + tc4);
    tile[r][tc4] = v.x; tile[r][tc4 + 1] = v.y; tile[r][tc4 + 2] = v.z; tile[r][tc4 + 3] = v.w;
  }
  __syncthreads();
#pragma unroll
  for (int it = 0; it < 2; ++it) {
    const int c = it * 32 + wc;
#pragma unroll
    for (int j = 0; j < 8; ++j) oA[it][j] = f2bf(tile[wr + j][c]);
  }
  __syncthreads();
#pragma unroll
  for (int it = 0; it < 4; ++it) {
    const int r = it * 16 + tr;
    float4 v = *reinterpret_cast<const float4*>(s + (size_t)(r0 + 64 + r) * C + c0 + tc4);
    tile[r][tc4] = v.x; tile[r][tc4 + 1] = v.y; tile[r][tc4 + 2] = v.z; tile[r][tc4 + 3] = v.w;
  }
  __syncthreads();
#pragma unroll
  for (int it = 0; it < 2; ++it) {
    const int c = it * 32 + wc;
    ushort8_t oB;
#pragma unroll
    for (int j = 0; j < 8; ++j) oB[j] = f2bf(tile[wr + j][c]);
    *reinterpret_cast<ushort8_t*>(d + (size_t)(c0 + c) * R + r0 + wr) = oA[it];
    *reinterpret_cast<ushort8_t*>(d + (size_t)(c0 + c) * R + r0 + 64 + wr) = oB;
  }
}

__device__ __forceinline__ void router_body(const float* __restrict__ hs,
                                            const float* __restrict__ gw,
                                            unsigned short* __restrict__ hsb,
                                            int* __restrict__ eid, float* __restrict__ wgt,
                                            int* __restrict__ counts, int rbid, char* smem) {
  float* s_gw = reinterpret_cast<float*>(smem);          // 32 KB
  int* s_cnt = reinterpret_cast<int*>(smem + 32768);     // 32 B
  const int th = threadIdx.x;
  for (int u = th; u < 2048; u += 256) {
    const f32x4 v = *reinterpret_cast<const f32x4*>(gw + u * 4);
    *reinterpret_cast<f32x4*>(&s_gw[(u ^ ((u >> 3) & 7)) * 4]) = v;
  }
  if (th < E_NUM) s_cnt[th] = 0;
  __syncthreads();

  const int l = th & 63, w = th >> 6;
#pragma unroll 1
  for (int tt = 0; tt < 4; ++tt) {
    const int t = rbid * 16 + w * 4 + tt;
    const float* hrow = hs + (size_t)t * H_DIM;
    unsigned short* brow = hsb + (size_t)t * H_DIM;
    float acc[E_NUM];
#pragma unroll
    for (int e = 0; e < E_NUM; ++e) acc[e] = 0.f;
#pragma unroll
    for (int i = 0; i < 4; ++i) {
      const int h0 = i * 256 + l * 4;
      const f32x4 x = *reinterpret_cast<const f32x4*>(hrow + h0);
      ushort4_t o = { f2bf(x[0]), f2bf(x[1]), f2bf(x[2]), f2bf(x[3]) };
      *reinterpret_cast<ushort4_t*>(brow + h0) = o;
#pragma unroll
      for (int j = 0; j < 4; ++j) {
        const int h = h0 + j;
        const int p0 = (h * 2) ^ ((h >> 2) & 7);
        const f32x4 g0 = *reinterpret_cast<const f32x4*>(&s_gw[p0 * 4]);
        const f32x4 g1 = *reinterpret_cast<const f32x4*>(&s_gw[(p0 ^ 1) * 4]);
        acc[0] += x[j] * g0[0]; acc[1] += x[j] * g0[1];
        acc[2] += x[j] * g0[2]; acc[3] += x[j] * g0[3];
        acc[4] += x[j] * g1[0]; acc[5] += x[j] * g1[1];
        acc[6] += x[j] * g1[2]; acc[7] += x[j] * g1[3];
      }
    }
#pragma unroll
    for (int e = 0; e < E_NUM; ++e) {
#pragma unroll
      for (int off = 1; off < 64; off <<= 1) acc[e] += __shfl_xor(acc[e], off);
    }
    if (l == 0) {
      int i1 = 0;
#pragma unroll
      for (int e = 1; e < E_NUM; ++e) if (acc[e] > acc[i1]) i1 = e;
      int i2 = (i1 == 0) ? 1 : 0;
#pragma unroll
      for (int e = 0; e < E_NUM; ++e) if (e != i1 && acc[e] > acc[i2]) i2 = e;
      const float e2 = __expf(acc[i2] - acc[i1]);
      const float inv = 1.f / (1.f + e2);
      eid[t * 2] = i1;     wgt[t * 2] = inv;
      eid[t * 2 + 1] = i2; wgt[t * 2 + 1] = e2 * inv;
      atomicAdd(&s_cnt[i1], 1);
      atomicAdd(&s_cnt[i2], 1);
    }
  }
  __syncthreads();
  if (th < E_NUM && s_cnt[th] > 0) atomicAdd(&counts[th], s_cnt[th]);
}

// ---- kernel1: router (bids 0..255) + w1 dual-transpose (256..3839) --------
__global__ __launch_bounds__(256) void prep1_kernel(
    const float* __restrict__ w1, const float* __restrict__ hs,
    const float* __restrict__ gw,
    unsigned short* __restrict__ w1t, unsigned short* __restrict__ hsb,
    int* __restrict__ eid, float* __restrict__ wgt, int* __restrict__ counts) {
  __shared__ char smem[33024];   // router: 32KB+32B; transpose: 16.6KB
  const int bid = blockIdx.x;
  if (bid < 256) {
    router_body(hs, gw, hsb, eid, wgt, counts, bid, smem);
    return;
  }
  const int idx = bid - 256;     // w1: R=1024, C=3584; 56c x 8 row-pairs per e
  const int e = idx / 448, rem = idx % 448;
  transpose_body2(w1, w1t, H_DIM, I_DIM, e, (rem % 56) * 64, (rem / 56) * 128, smem);
}

// ---------------- scatter: block-local histogram + range reservation -------
__global__ void scatter_kernel(const int* __restrict__ eid, const int* __restrict__ counts,
                               int* __restrict__ fill, int* __restrict__ rowmap,
                               int* __restrict__ posmap) {
  __shared__ int hist[E_NUM], base[E_NUM];
  const int th = threadIdx.x;
  const int p = blockIdx.x * 256 + th;
  if (th < E_NUM) hist[th] = 0;
  __syncthreads();
  const int e = eid[p];
  const int rloc = atomicAdd(&hist[e], 1);
  __syncthreads();
  if (th < E_NUM) base[th] = (hist[th] > 0) ? atomicAdd(&fill[th], hist[th]) : 0;
  __syncthreads();
  int off = 0;
#pragma unroll
  for (int i = 0; i < E_NUM; ++i) off += (i < e) ? counts[i] : 0;
  const int pos = off + base[e] + rloc;
  rowmap[pos] = p;
  posmap[p] = pos;
}

// ---------------- combine: out[t] = res[pos(2t)] + res[pos(2t+1)] ----------
__global__ void combine_kernel(const float* __restrict__ res, const int* __restrict__ posmap,
                               float* __restrict__ out) {
  const int t = blockIdx.x;
  const int th = threadIdx.x;
  const int a = posmap[t * 2];
  const int b = posmap[t * 2 + 1];
  const float4 va = *reinterpret_cast<const float4*>(res + (size_t)a * H_DIM + th * 4);
  const float4 vb = *reinterpret_cast<const float4*>(res + (size_t)b * H_DIM + th * 4);
  float4 o = { va.x + vb.x, va.y + vb.y, va.z + vb.z, va.w + vb.w };
  *reinterpret_cast<float4*>(out + (size_t)t * H_DIM + th * 4) = o;
}

// ---- kernel2: gemm0 (bids 0..2015, supertiled) + w2 dual-transpose --------
// gemm0 is latency-bound (25% MfmaUtil, 1.4 TB/s): w2t blocks soak idle BW.
__global__ __launch_bounds__(256, 4) void gemm0_w2t_kernel(
    const unsigned short* __restrict__ hsb, const unsigned short* __restrict__ w1t,
    unsigned short* __restrict__ act,
    const float* __restrict__ w2, unsigned short* __restrict__ w2t,
    const int* __restrict__ counts, const int* __restrict__ rowmap) {
  __shared__ char smem[(BM * BK + BN * BK) * 2];   // 32 KB
  const int bid = blockIdx.x;
  if (bid >= G0_NWG) {
    const int idx = bid - G0_NWG;  // w2: R=3584, C=1024; 16c x 28 row-pairs per e
    const int e = idx / 448, rem = idx % 448;
    transpose_body2(w2, w2t, I_DIM, H_DIM, e, (rem % 16) * 64, (rem / 16) * 128, smem);
    return;
  }
  unsigned short* As = reinterpret_cast<unsigned short*>(smem);
  unsigned short* Bs = As + BM * BK;

  // T1 bijective XCD swizzle + 9rt x 4ct supertile (A 2.3MB + B 1MB in L2)
  constexpr int CHUNK = G0_NWG / 8;   // 252
  const int wgid = (bid & 7) * CHUNK + (bid >> 3);
  const int l = wgid % CHUNK;
  const int sg = l / 36;
  const int q = l % 36;
  const int rt = (wgid / CHUNK) * 9 + q % 9;
  const int ct = sg * 4 + q / 9;

  // expert walk from counts (prefix on the fly)
  int e = -1, loc_rt = 0, off_e = 0, cnt = 0;
  {
    int acc_t = 0, off = 0;
#pragma unroll
    for (int ee = 0; ee < E_NUM; ++ee) {
      const int c = counts[ee];
      const int nt = (c + BM - 1) >> 7;
      if (e < 0 && rt < acc_t + nt) { e = ee; loc_rt = rt - acc_t; off_e = off; cnt = c; }
      acc_t += nt; off += c;
    }
  }
  if (e < 0) return;

  const int cnt_local = min(BM, cnt - loc_rt * BM);
  const int r_base = off_e + loc_rt * BM;
  const int th = threadIdx.x;
  const int lane = th & 63, wid = th >> 6;

  const int n0 = ct * BN;
  const unsigned short* wbase = w1t + (size_t)e * ((size_t)I_DIM * H_DIM) + (size_t)n0 * H_DIM;

  // staging: LDS dest linear; source chunk pre-swizzled: cg = (lane&7)^(row&7)
  const int srow = lane >> 3;
  const int cg = (lane & 7) ^ srow;
  const char* aptr[4];
  const char* bptr[4];
#pragma unroll
  for (int i = 0; i < 4; ++i) {
    const int r = i * 32 + wid * 8 + srow;
    const int rr = (r < cnt_local) ? r : (cnt_local - 1);
    const int tok = rowmap[off_e + loc_rt * BM + rr] >> 1;
    aptr[i] = (const char*)(hsb + (size_t)tok * H_DIM) + cg * 16;
    bptr[i] = (const char*)(wbase + (size_t)r * H_DIM) + cg * 16;
  }
  unsigned short* dstA[4];
  unsigned short* dstB[4];
#pragma unroll
  for (int i = 0; i < 4; ++i) {
    dstA[i] = &As[(i * 32 + wid * 8) * BK];   // wave-uniform
    dstB[i] = &Bs[(i * 32 + wid * 8) * BK];
  }

  f32x4 acc[4][4];
#pragma unroll
  for (int m = 0; m < 4; ++m)
#pragma unroll
    for (int n = 0; n < 4; ++n) acc[m][n] = (f32x4){0.f, 0.f, 0.f, 0.f};

  const int wm = (wid >> 1) * 64;
  const int wn = (wid & 1) * 64;
  const int fr = lane & 15;
  const int fq = lane >> 4;
  const int sxor = fr & 7;

  for (int k0 = 0; k0 < H_DIM; k0 += BK) {
    const int kb = k0 * 2;
#pragma unroll
    for (int i = 0; i < 4; ++i) gload16(aptr[i] + kb, dstA[i]);
#pragma unroll
    for (int i = 0; i < 4; ++i) gload16(bptr[i] + kb, dstB[i]);
    __syncthreads();   // drains vmcnt before s_barrier

#pragma unroll
    for (int kk = 0; kk < 2; ++kk) {
      bf16x8 af[4], bf[4];
#pragma unroll
      for (int m = 0; m < 4; ++m)
        af[m] = *reinterpret_cast<const bf16x8*>(
            &As[(wm + m * 16 + fr) * BK + ((kk * 4 + fq) ^ sxor) * 8]);
#pragma unroll
      for (int n = 0; n < 4; ++n)
        bf[n] = *reinterpret_cast<const bf16x8*>(
            &Bs[(wn + n * 16 + fr) * BK + ((kk * 4 + fq) ^ sxor) * 8]);
#pragma unroll
      for (int m = 0; m < 4; ++m)
#pragma unroll
        for (int n = 0; n < 4; ++n)
          acc[m][n] = __builtin_amdgcn_mfma_f32_16x16x32_bf16(af[m], bf[n], acc[m][n], 0, 0, 0);
    }
    __syncthreads();
  }

  // ---- epilogue: silu -> act bf16
#pragma unroll
  for (int m = 0; m < 4; ++m) {
    const int row = wm + m * 16 + fq * 4;
#pragma unroll
    for (int n = 0; n < 4; ++n) {
      const int col = wn + n * 16 + fr;
#pragma unroll
      for (int r = 0; r < 4; ++r) {
        const int rw = row + r;
        if (rw < cnt_local) {
          const float x = acc[m][n][r];
          const float s = x / (1.f + __expf(-x));
          act[(size_t)(r_base + rw) * I_DIM + n0 + col] = f2bf(s);
        }
      }
    }
  }
}

// ---------------- gemm1 (128x128, band-of-2rt chunks, plain res stores) ----
__launch_bounds__(256, 4)
__global__ void moe_gemm1(const unsigned short* __restrict__ w2t,
                          const unsigned short* __restrict__ act_in,
                          float* __restrict__ res,
                          const int* __restrict__ counts,
                          const int* __restrict__ rowmap,
                          const float* __restrict__ wgt) {
  constexpr int NCT = H_DIM / BN;            // 8
  constexpr int NWG = MAX_RT * NCT;          // 576
  constexpr int CHUNK = NWG / 8;             // 72

  __shared__ unsigned short As[BM * BK];
  __shared__ unsigned short Bs[BN * BK];
  __shared__ float s_w[BM];

  // T1 bijective XCD swizzle; band of 2rt x 8ct within each 72-wgid chunk
  const int bid = blockIdx.x;
  const int wgid = (bid & 7) * CHUNK + (bid >> 3);
  int rt, ct;
  {
    const int c9 = (wgid / CHUNK) * 9;
    const int l = wgid % CHUNK;
    if (l < 64) {
      const int band = l >> 4, inner = l & 15;
      rt = c9 + band * 2 + (inner & 1);
      ct = inner >> 1;
    } else {
      rt = c9 + 8;
      ct = l - 64;
    }
  }

  // expert walk from counts (prefix on the fly)
  int e = -1, loc_rt = 0, off_e = 0, cnt = 0;
  {
    int acc_t = 0, off = 0;
#pragma unroll
    for (int ee = 0; ee < E_NUM; ++ee) {
      const int c = counts[ee];
      const int nt = (c + BM - 1) >> 7;
      if (e < 0 && rt < acc_t + nt) { e = ee; loc_rt = rt - acc_t; off_e = off; cnt = c; }
      acc_t += nt; off += c;
    }
  }
  if (e < 0) return;

  const int cnt_local = min(BM, cnt - loc_rt * BM);
  const int r_base = off_e + loc_rt * BM;
  const int th = threadIdx.x;
  const int lane = th & 63, wid = th >> 6;

  if (th < BM) {
    int r = loc_rt * BM + th;
    if (r >= cnt) r = cnt - 1;
    s_w[th] = wgt[rowmap[off_e + r]];
  }

  const int n0 = ct * BN;
  const unsigned short* wbase = w2t + (size_t)e * ((size_t)I_DIM * H_DIM) + (size_t)n0 * I_DIM;

  const int srow = lane >> 3;
  const int cg = (lane & 7) ^ srow;
  const char* aptr[4];
  const char* bptr[4];
#pragma unroll
  for (int i = 0; i < 4; ++i) {
    const int r = i * 32 + wid * 8 + srow;
    const int rr = (r < cnt_local) ? r : (cnt_local - 1);
    aptr[i] = (const char*)(act_in + (size_t)(r_base + rr) * I_DIM) + cg * 16;
    bptr[i] = (const char*)(wbase + (size_t)r * I_DIM) + cg * 16;
  }
  unsigned short* dstA[4];
  unsigned short* dstB[4];
#pragma unroll
  for (int i = 0; i < 4; ++i) {
    dstA[i] = &As[(i * 32 + wid * 8) * BK];
    dstB[i] = &Bs[(i * 32 + wid * 8) * BK];
  }

  f32x4 acc[4][4];
#pragma unroll
  for (int m = 0; m < 4; ++m)
#pragma unroll
    for (int n = 0; n < 4; ++n) acc[m][n] = (f32x4){0.f, 0.f, 0.f, 0.f};

  const int wm = (wid >> 1) * 64;
  const int wn = (wid & 1) * 64;
  const int fr = lane & 15;
  const int fq = lane >> 4;
  const int sxor = fr & 7;

  for (int k0 = 0; k0 < I_DIM; k0 += BK) {
    const int kb = k0 * 2;
#pragma unroll
    for (int i = 0; i < 4; ++i) gload16(aptr[i] + kb, dstA[i]);
#pragma unroll
    for (int i = 0; i < 4; ++i) gload16(bptr[i] + kb, dstB[i]);
    __syncthreads();

#pragma unroll
    for (int kk = 0; kk < 2; ++kk) {
      bf16x8 af[4], bf[4];
#pragma unroll
      for (int m = 0; m < 4; ++m)
        af[m] = *reinterpret_cast<const bf16x8*>(
            &As[(wm + m * 16 + fr) * BK + ((kk * 4 + fq) ^ sxor) * 8]);
#pragma unroll
      for (int n = 0; n < 4; ++n)
        bf[n] = *reinterpret_cast<const bf16x8*>(
            &Bs[(wn + n * 16 + fr) * BK + ((kk * 4 + fq) ^ sxor) * 8]);
#pragma unroll
      for (int m = 0; m < 4; ++m)
#pragma unroll
        for (int n = 0; n < 4; ++n)
          acc[m][n] = __builtin_amdgcn_mfma_f32_16x16x32_bf16(af[m], bf[n], acc[m][n], 0, 0, 0);
    }
    __syncthreads();
  }

#pragma unroll
  for (int m = 0; m < 4; ++m) {
    const int row = wm + m * 16 + fq * 4;
#pragma unroll
    for (int n = 0; n < 4; ++n) {
      const int col = wn + n * 16 + fr;
#pragma unroll
      for (int r = 0; r < 4; ++r) {
        const int rw = row + r;
        if (rw < cnt_local)
          res[(size_t)(r_base + rw) * H_DIM + n0 + col] = acc[m][n][r] * s_w[rw];
      }
    }
  }
}

// ---------------- launch ----------------
extern "C" void kernel_launch(void* const* d_in, const int* in_sizes, int n_in,
                              void* d_out, int out_size, void* d_ws, size_t ws_size,
                              hipStream_t stream) {
  const float* hs = (const float*)d_in[0];
  const float* gw = (const float*)d_in[1];
  const float* w1 = (const float*)d_in[2];
  const float* w2 = (const float*)d_in[3];
  float* out = (float*)d_out;

  char* ws = (char*)d_ws;
  const size_t WMAT = (size_t)E_NUM * I_DIM * H_DIM * 2;   // 58,720,256 B
  unsigned short* w1t = (unsigned short*)ws;                // [E][I][H] bf16
  unsigned short* w2t = (unsigned short*)(ws + WMAT);       // [E][H][I] bf16
  unsigned short* act = (unsigned short*)(ws + 2 * WMAT);   // [NPAIR][I] bf16
  unsigned short* hsb = (unsigned short*)(ws + 3 * WMAT);   // [T][H] bf16
  // res aliases w1t: dead after gemm0_w2t completes (stream-ordered).
  float* res = (float*)w1t;                                 // [NPAIR][H] fp32
  char* small = ws + 3 * WMAT + (size_t)T_TOK * H_DIM * 2;
  int* eid = (int*)small;                          // NPAIR
  float* wgt = (float*)(small + NPAIR * 4);        // NPAIR
  int* rowmap = (int*)(small + 2 * NPAIR * 4);     // NPAIR
  int* posmap = (int*)(small + 3 * NPAIR * 4);     // NPAIR
  int* counts = (int*)(small + 4 * NPAIR * 4);     // 8
  int* fill = counts + 8;                          // 8

  hipMemsetAsync(counts, 0, 16 * sizeof(int), stream);

  prep1_kernel<<<256 + WT_NB, 256, 0, stream>>>(w1, hs, gw, w1t, hsb, eid, wgt, counts);
  scatter_kernel<<<NPAIR / 256, 256, 0, stream>>>(eid, counts, fill, rowmap, posmap);

  gemm0_w2t_kernel<<<G0_NWG + WT_NB, 256, 0, stream>>>(
      hsb, w1t, act, w2, w2t, counts, rowmap);
  moe_gemm1<<<MAX_RT * (H_DIM / BN), 256, 0, stream>>>(
      w2t, act, res, counts, rowmap, wgt);

  combine_kernel<<<T_TOK, 256, 0, stream>>>(res, posmap, out);
}

// Round 22
// 241.791 us; speedup vs baseline: 5.0229x; 1.0131x over previous
//
#include <hip/hip_runtime.h>
#include <hip/hip_bf16.h>

// ---------------- problem constants (match setup_inputs) ----------------
#define T_TOK 4096
#define H_DIM 1024
#define E_NUM 8
#define I_DIM 3584
#define NPAIR (T_TOK * 2)   // top_k = 2
#define MAX_RT 72           // worst-case total row tiles: sum ceil(cnt_e/128) <= 64+7

#define BM 128
#define BN 128
#define BK 64
#define G0_NWG (MAX_RT * (I_DIM / BN))   // 2016 gemm0 blocks
#define WT_NB 3584                       // dual-tile transpose blocks per matrix

typedef __attribute__((ext_vector_type(8))) short bf16x8;
typedef __attribute__((ext_vector_type(4))) float f32x4;
typedef __attribute__((ext_vector_type(8))) unsigned short ushort8_t;
typedef __attribute__((ext_vector_type(4))) unsigned short ushort4_t;

// RNE fp32 -> bf16
__device__ __forceinline__ unsigned short f2bf(float x) {
  unsigned int u = __float_as_uint(x);
  unsigned int r = (u + 0x7FFFu + ((u >> 16) & 1u)) >> 16;
  return (unsigned short)r;
}
__device__ __forceinline__ float bf2f(unsigned short u) {
  return __uint_as_float((unsigned int)u << 16);
}

// async 16B global -> LDS (dest: wave-uniform base, HW adds lane*16)
__device__ __forceinline__ void gload16(const void* g, unsigned short* l) {
  __builtin_amdgcn_global_load_lds(
      (const __attribute__((address_space(1))) void*)g,
      (__attribute__((address_space(3))) void*)l, 16, 0, 0);
}

// ---------------- dual-tile transpose (2x 64-row passes, fused 256B writes) -
__device__ __forceinline__ void transpose_body2(const float* __restrict__ src,
                                                unsigned short* __restrict__ dst,
                                                int R, int C, int e, int c0, int r0,
                                                char* smem) {
  float (*tile)[65] = reinterpret_cast<float (*)[65]>(smem);
  const float* s = src + (size_t)e * R * C;
  unsigned short* d = dst + (size_t)e * R * C;
  const int th = threadIdx.x;
  const int tr = th >> 4;
  const int tc4 = (th & 15) * 4;
  const int wc = th >> 3;
  const int wr = (th & 7) * 8;
  ushort8_t oA[2];
#pragma unroll
  for (int it = 0; it < 4; ++it) {
    const int r = it * 16 + tr;
    float4 v = *reinterpret_cast<const float4*>(s + (size_t)(r0 + r) * C + c0 + tc4);
    tile[r][tc4] = v.x; tile[r][tc4 + 1] = v.y; tile[r][tc4 + 2] = v.z; tile[r][tc4 + 3] = v.w;
  }
  __syncthreads();
#pragma unroll
  for (int it = 0; it < 2; ++it) {
    const int c = it * 32 + wc;
#pragma unroll
    for (int j = 0; j < 8; ++j) oA[it][j] = f2bf(tile[wr + j][c]);
  }
  __syncthreads();
#pragma unroll
  for (int it = 0; it < 4; ++it) {
    const int r = it * 16 + tr;
    float4 v = *reinterpret_cast<const float4*>(s + (size_t)(r0 + 64 + r) * C + c0 + tc4);
    tile[r][tc4] = v.x; tile[r][tc4 + 1] = v.y; tile[r][tc4 + 2] = v.z; tile[r][tc4 + 3] = v.w;
  }
  __syncthreads();
#pragma unroll
  for (int it = 0; it < 2; ++it) {
    const int c = it * 32 + wc;
    ushort8_t oB;
#pragma unroll
    for (int j = 0; j < 8; ++j) oB[j] = f2bf(tile[wr + j][c]);
    *reinterpret_cast<ushort8_t*>(d + (size_t)(c0 + c) * R + r0 + wr) = oA[it];
    *reinterpret_cast<ushort8_t*>(d + (size_t)(c0 + c) * R + r0 + 64 + wr) = oB;
  }
}

__device__ __forceinline__ void router_body(const float* __restrict__ hs,
                                            const float* __restrict__ gw,
                                            unsigned short* __restrict__ hsb,
                                            int* __restrict__ eid, float* __restrict__ wgt,
                                            int* __restrict__ counts, int rbid, char* smem) {
  float* s_gw = reinterpret_cast<float*>(smem);          // 32 KB
  int* s_cnt = reinterpret_cast<int*>(smem + 32768);     // 32 B
  const int th = threadIdx.x;
  for (int u = th; u < 2048; u += 256) {
    const f32x4 v = *reinterpret_cast<const f32x4*>(gw + u * 4);
    *reinterpret_cast<f32x4*>(&s_gw[(u ^ ((u >> 3) & 7)) * 4]) = v;
  }
  if (th < E_NUM) s_cnt[th] = 0;
  __syncthreads();

  const int l = th & 63, w = th >> 6;
#pragma unroll 1
  for (int tt = 0; tt < 4; ++tt) {
    const int t = rbid * 16 + w * 4 + tt;
    const float* hrow = hs + (size_t)t * H_DIM;
    unsigned short* brow = hsb + (size_t)t * H_DIM;
    float acc[E_NUM];
#pragma unroll
    for (int e = 0; e < E_NUM; ++e) acc[e] = 0.f;
#pragma unroll
    for (int i = 0; i < 4; ++i) {
      const int h0 = i * 256 + l * 4;
      const f32x4 x = *reinterpret_cast<const f32x4*>(hrow + h0);
      ushort4_t o = { f2bf(x[0]), f2bf(x[1]), f2bf(x[2]), f2bf(x[3]) };
      *reinterpret_cast<ushort4_t*>(brow + h0) = o;
#pragma unroll
      for (int j = 0; j < 4; ++j) {
        const int h = h0 + j;
        const int p0 = (h * 2) ^ ((h >> 2) & 7);
        const f32x4 g0 = *reinterpret_cast<const f32x4*>(&s_gw[p0 * 4]);
        const f32x4 g1 = *reinterpret_cast<const f32x4*>(&s_gw[(p0 ^ 1) * 4]);
        acc[0] += x[j] * g0[0]; acc[1] += x[j] * g0[1];
        acc[2] += x[j] * g0[2]; acc[3] += x[j] * g0[3];
        acc[4] += x[j] * g1[0]; acc[5] += x[j] * g1[1];
        acc[6] += x[j] * g1[2]; acc[7] += x[j] * g1[3];
      }
    }
#pragma unroll
    for (int e = 0; e < E_NUM; ++e) {
#pragma unroll
      for (int off = 1; off < 64; off <<= 1) acc[e] += __shfl_xor(acc[e], off);
    }
    if (l == 0) {
      int i1 = 0;
#pragma unroll
      for (int e = 1; e < E_NUM; ++e) if (acc[e] > acc[i1]) i1 = e;
      int i2 = (i1 == 0) ? 1 : 0;
#pragma unroll
      for (int e = 0; e < E_NUM; ++e) if (e != i1 && acc[e] > acc[i2]) i2 = e;
      const float e2 = __expf(acc[i2] - acc[i1]);
      const float inv = 1.f / (1.f + e2);
      eid[t * 2] = i1;     wgt[t * 2] = inv;
      eid[t * 2 + 1] = i2; wgt[t * 2 + 1] = e2 * inv;
      atomicAdd(&s_cnt[i1], 1);
      atomicAdd(&s_cnt[i2], 1);
    }
  }
  __syncthreads();
  if (th < E_NUM && s_cnt[th] > 0) atomicAdd(&counts[th], s_cnt[th]);
}

// ---- kernel1: router (bids 0..255) + w1 dual-transpose (256..3839) --------
__global__ __launch_bounds__(256) void prep1_kernel(
    const float* __restrict__ w1, const float* __restrict__ hs,
    const float* __restrict__ gw,
    unsigned short* __restrict__ w1t, unsigned short* __restrict__ hsb,
    int* __restrict__ eid, float* __restrict__ wgt, int* __restrict__ counts) {
  __shared__ char smem[33024];   // router: 32KB+32B; transpose: 16.6KB
  const int bid = blockIdx.x;
  if (bid < 256) {
    router_body(hs, gw, hsb, eid, wgt, counts, bid, smem);
    return;
  }
  const int idx = bid - 256;     // w1: R=1024, C=3584; 56c x 8 row-pairs per e
  const int e = idx / 448, rem = idx % 448;
  transpose_body2(w1, w1t, H_DIM, I_DIM, e, (rem % 56) * 64, (rem / 56) * 128, smem);
}

// ---------------- scatter: block-local histogram + range reservation -------
__global__ void scatter_kernel(const int* __restrict__ eid, const int* __restrict__ counts,
                               int* __restrict__ fill, int* __restrict__ rowmap,
                               int* __restrict__ posmap) {
  __shared__ int hist[E_NUM], base[E_NUM];
  const int th = threadIdx.x;
  const int p = blockIdx.x * 256 + th;
  if (th < E_NUM) hist[th] = 0;
  __syncthreads();
  const int e = eid[p];
  const int rloc = atomicAdd(&hist[e], 1);
  __syncthreads();
  if (th < E_NUM) base[th] = (hist[th] > 0) ? atomicAdd(&fill[th], hist[th]) : 0;
  __syncthreads();
  int off = 0;
#pragma unroll
  for (int i = 0; i < E_NUM; ++i) off += (i < e) ? counts[i] : 0;
  const int pos = off + base[e] + rloc;
  rowmap[pos] = p;
  posmap[p] = pos;
}

// ------- combine: out[t] = res_bf16[pos(2t)] + res_bf16[pos(2t+1)] ---------
__global__ void combine_kernel(const unsigned short* __restrict__ res,
                               const int* __restrict__ posmap,
                               float* __restrict__ out) {
  const int t = blockIdx.x;
  const int th = threadIdx.x;
  const ushort4_t va = *reinterpret_cast<const ushort4_t*>(
      res + (size_t)posmap[t * 2] * H_DIM + th * 4);
  const ushort4_t vb = *reinterpret_cast<const ushort4_t*>(
      res + (size_t)posmap[t * 2 + 1] * H_DIM + th * 4);
  float4 o = { bf2f(va[0]) + bf2f(vb[0]), bf2f(va[1]) + bf2f(vb[1]),
               bf2f(va[2]) + bf2f(vb[2]), bf2f(va[3]) + bf2f(vb[3]) };
  *reinterpret_cast<float4*>(out + (size_t)t * H_DIM + th * 4) = o;
}

// ---- kernel2: gemm0 (bids 0..2015, supertiled) + w2 dual-transpose --------
// gemm0 is latency-bound (25% MfmaUtil, 1.4 TB/s): w2t blocks soak idle BW.
__global__ __launch_bounds__(256, 4) void gemm0_w2t_kernel(
    const unsigned short* __restrict__ hsb, const unsigned short* __restrict__ w1t,
    unsigned short* __restrict__ act,
    const float* __restrict__ w2, unsigned short* __restrict__ w2t,
    const int* __restrict__ counts, const int* __restrict__ rowmap) {
  __shared__ char smem[(BM * BK + BN * BK) * 2];   // 32 KB
  const int bid = blockIdx.x;
  if (bid >= G0_NWG) {
    const int idx = bid - G0_NWG;  // w2: R=3584, C=1024; 16c x 28 row-pairs per e
    const int e = idx / 448, rem = idx % 448;
    transpose_body2(w2, w2t, I_DIM, H_DIM, e, (rem % 16) * 64, (rem / 16) * 128, smem);
    return;
  }
  unsigned short* As = reinterpret_cast<unsigned short*>(smem);
  unsigned short* Bs = As + BM * BK;

  // T1 bijective XCD swizzle + 9rt x 4ct supertile (A 2.3MB + B 1MB in L2)
  constexpr int CHUNK = G0_NWG / 8;   // 252
  const int wgid = (bid & 7) * CHUNK + (bid >> 3);
  const int l = wgid % CHUNK;
  const int sg = l / 36;
  const int q = l % 36;
  const int rt = (wgid / CHUNK) * 9 + q % 9;
  const int ct = sg * 4 + q / 9;

  // expert walk from counts (prefix on the fly)
  int e = -1, loc_rt = 0, off_e = 0, cnt = 0;
  {
    int acc_t = 0, off = 0;
#pragma unroll
    for (int ee = 0; ee < E_NUM; ++ee) {
      const int c = counts[ee];
      const int nt = (c + BM - 1) >> 7;
      if (e < 0 && rt < acc_t + nt) { e = ee; loc_rt = rt - acc_t; off_e = off; cnt = c; }
      acc_t += nt; off += c;
    }
  }
  if (e < 0) return;

  const int cnt_local = min(BM, cnt - loc_rt * BM);
  const int r_base = off_e + loc_rt * BM;
  const int th = threadIdx.x;
  const int lane = th & 63, wid = th >> 6;

  const int n0 = ct * BN;
  const unsigned short* wbase = w1t + (size_t)e * ((size_t)I_DIM * H_DIM) + (size_t)n0 * H_DIM;

  // staging: LDS dest linear; source chunk pre-swizzled: cg = (lane&7)^(row&7)
  const int srow = lane >> 3;
  const int cg = (lane & 7) ^ srow;
  const char* aptr[4];
  const char* bptr[4];
#pragma unroll
  for (int i = 0; i < 4; ++i) {
    const int r = i * 32 + wid * 8 + srow;
    const int rr = (r < cnt_local) ? r : (cnt_local - 1);
    const int tok = rowmap[off_e + loc_rt * BM + rr] >> 1;
    aptr[i] = (const char*)(hsb + (size_t)tok * H_DIM) + cg * 16;
    bptr[i] = (const char*)(wbase + (size_t)r * H_DIM) + cg * 16;
  }
  unsigned short* dstA[4];
  unsigned short* dstB[4];
#pragma unroll
  for (int i = 0; i < 4; ++i) {
    dstA[i] = &As[(i * 32 + wid * 8) * BK];   // wave-uniform
    dstB[i] = &Bs[(i * 32 + wid * 8) * BK];
  }

  f32x4 acc[4][4];
#pragma unroll
  for (int m = 0; m < 4; ++m)
#pragma unroll
    for (int n = 0; n < 4; ++n) acc[m][n] = (f32x4){0.f, 0.f, 0.f, 0.f};

  const int wm = (wid >> 1) * 64;
  const int wn = (wid & 1) * 64;
  const int fr = lane & 15;
  const int fq = lane >> 4;
  const int sxor = fr & 7;

  for (int k0 = 0; k0 < H_DIM; k0 += BK) {
    const int kb = k0 * 2;
#pragma unroll
    for (int i = 0; i < 4; ++i) gload16(aptr[i] + kb, dstA[i]);
#pragma unroll
    for (int i = 0; i < 4; ++i) gload16(bptr[i] + kb, dstB[i]);
    __syncthreads();   // drains vmcnt before s_barrier

#pragma unroll
    for (int kk = 0; kk < 2; ++kk) {
      bf16x8 af[4], bf[4];
#pragma unroll
      for (int m = 0; m < 4; ++m)
        af[m] = *reinterpret_cast<const bf16x8*>(
            &As[(wm + m * 16 + fr) * BK + ((kk * 4 + fq) ^ sxor) * 8]);
#pragma unroll
      for (int n = 0; n < 4; ++n)
        bf[n] = *reinterpret_cast<const bf16x8*>(
            &Bs[(wn + n * 16 + fr) * BK + ((kk * 4 + fq) ^ sxor) * 8]);
#pragma unroll
      for (int m = 0; m < 4; ++m)
#pragma unroll
        for (int n = 0; n < 4; ++n)
          acc[m][n] = __builtin_amdgcn_mfma_f32_16x16x32_bf16(af[m], bf[n], acc[m][n], 0, 0, 0);
    }
    __syncthreads();
  }

  // ---- epilogue: silu -> act bf16
#pragma unroll
  for (int m = 0; m < 4; ++m) {
    const int row = wm + m * 16 + fq * 4;
#pragma unroll
    for (int n = 0; n < 4; ++n) {
      const int col = wn + n * 16 + fr;
#pragma unroll
      for (int r = 0; r < 4; ++r) {
        const int rw = row + r;
        if (rw < cnt_local) {
          const float x = acc[m][n][r];
          const float s = x / (1.f + __expf(-x));
          act[(size_t)(r_base + rw) * I_DIM + n0 + col] = f2bf(s);
        }
      }
    }
  }
}

// -------- gemm1 (128x128, band-of-2rt chunks, bf16 res stores) -------------
__launch_bounds__(256, 4)
__global__ void moe_gemm1(const unsigned short* __restrict__ w2t,
                          const unsigned short* __restrict__ act_in,
                          unsigned short* __restrict__ res,
                          const int* __restrict__ counts,
                          const int* __restrict__ rowmap,
                          const float* __restrict__ wgt) {
  constexpr int NCT = H_DIM / BN;            // 8
  constexpr int NWG = MAX_RT * NCT;          // 576
  constexpr int CHUNK = NWG / 8;             // 72

  __shared__ unsigned short As[BM * BK];
  __shared__ unsigned short Bs[BN * BK];
  __shared__ float s_w[BM];

  // T1 bijective XCD swizzle; band of 2rt x 8ct within each 72-wgid chunk
  const int bid = blockIdx.x;
  const int wgid = (bid & 7) * CHUNK + (bid >> 3);
  int rt, ct;
  {
    const int c9 = (wgid / CHUNK) * 9;
    const int l = wgid % CHUNK;
    if (l < 64) {
      const int band = l >> 4, inner = l & 15;
      rt = c9 + band * 2 + (inner & 1);
      ct = inner >> 1;
    } else {
      rt = c9 + 8;
      ct = l - 64;
    }
  }

  // expert walk from counts (prefix on the fly)
  int e = -1, loc_rt = 0, off_e = 0, cnt = 0;
  {
    int acc_t = 0, off = 0;
#pragma unroll
    for (int ee = 0; ee < E_NUM; ++ee) {
      const int c = counts[ee];
      const int nt = (c + BM - 1) >> 7;
      if (e < 0 && rt < acc_t + nt) { e = ee; loc_rt = rt - acc_t; off_e = off; cnt = c; }
      acc_t += nt; off += c;
    }
  }
  if (e < 0) return;

  const int cnt_local = min(BM, cnt - loc_rt * BM);
  const int r_base = off_e + loc_rt * BM;
  const int th = threadIdx.x;
  const int lane = th & 63, wid = th >> 6;

  if (th < BM) {
    int r = loc_rt * BM + th;
    if (r >= cnt) r = cnt - 1;
    s_w[th] = wgt[rowmap[off_e + r]];
  }

  const int n0 = ct * BN;
  const unsigned short* wbase = w2t + (size_t)e * ((size_t)I_DIM * H_DIM) + (size_t)n0 * I_DIM;

  const int srow = lane >> 3;
  const int cg = (lane & 7) ^ srow;
  const char* aptr[4];
  const char* bptr[4];
#pragma unroll
  for (int i = 0; i < 4; ++i) {
    const int r = i * 32 + wid * 8 + srow;
    const int rr = (r < cnt_local) ? r : (cnt_local - 1);
    aptr[i] = (const char*)(act_in + (size_t)(r_base + rr) * I_DIM) + cg * 16;
    bptr[i] = (const char*)(wbase + (size_t)r * I_DIM) + cg * 16;
  }
  unsigned short* dstA[4];
  unsigned short* dstB[4];
#pragma unroll
  for (int i = 0; i < 4; ++i) {
    dstA[i] = &As[(i * 32 + wid * 8) * BK];
    dstB[i] = &Bs[(i * 32 + wid * 8) * BK];
  }

  f32x4 acc[4][4];
#pragma unroll
  for (int m = 0; m < 4; ++m)
#pragma unroll
    for (int n = 0; n < 4; ++n) acc[m][n] = (f32x4){0.f, 0.f, 0.f, 0.f};

  const int wm = (wid >> 1) * 64;
  const int wn = (wid & 1) * 64;
  const int fr = lane & 15;
  const int fq = lane >> 4;
  const int sxor = fr & 7;

  for (int k0 = 0; k0 < I_DIM; k0 += BK) {
    const int kb = k0 * 2;
#pragma unroll
    for (int i = 0; i < 4; ++i) gload16(aptr[i] + kb, dstA[i]);
#pragma unroll
    for (int i = 0; i < 4; ++i) gload16(bptr[i] + kb, dstB[i]);
    __syncthreads();

#pragma unroll
    for (int kk = 0; kk < 2; ++kk) {
      bf16x8 af[4], bf[4];
#pragma unroll
      for (int m = 0; m < 4; ++m)
        af[m] = *reinterpret_cast<const bf16x8*>(
            &As[(wm + m * 16 + fr) * BK + ((kk * 4 + fq) ^ sxor) * 8]);
#pragma unroll
      for (int n = 0; n < 4; ++n)
        bf[n] = *reinterpret_cast<const bf16x8*>(
            &Bs[(wn + n * 16 + fr) * BK + ((kk * 4 + fq) ^ sxor) * 8]);
#pragma unroll
      for (int m = 0; m < 4; ++m)
#pragma unroll
        for (int n = 0; n < 4; ++n)
          acc[m][n] = __builtin_amdgcn_mfma_f32_16x16x32_bf16(af[m], bf[n], acc[m][n], 0, 0, 0);
    }
    __syncthreads();
  }

#pragma unroll
  for (int m = 0; m < 4; ++m) {
    const int row = wm + m * 16 + fq * 4;
#pragma unroll
    for (int n = 0; n < 4; ++n) {
      const int col = wn + n * 16 + fr;
#pragma unroll
      for (int r = 0; r < 4; ++r) {
        const int rw = row + r;
        if (rw < cnt_local)
          res[(size_t)(r_base + rw) * H_DIM + n0 + col] = f2bf(acc[m][n][r] * s_w[rw]);
      }
    }
  }
}

// ---------------- launch ----------------
extern "C" void kernel_launch(void* const* d_in, const int* in_sizes, int n_in,
                              void* d_out, int out_size, void* d_ws, size_t ws_size,
                              hipStream_t stream) {
  const float* hs = (const float*)d_in[0];
  const float* gw = (const float*)d_in[1];
  const float* w1 = (const float*)d_in[2];
  const float* w2 = (const float*)d_in[3];
  float* out = (float*)d_out;

  char* ws = (char*)d_ws;
  const size_t WMAT = (size_t)E_NUM * I_DIM * H_DIM * 2;   // 58,720,256 B
  unsigned short* w1t = (unsigned short*)ws;                // [E][I][H] bf16
  unsigned short* w2t = (unsigned short*)(ws + WMAT);       // [E][H][I] bf16
  unsigned short* act = (unsigned short*)(ws + 2 * WMAT);   // [NPAIR][I] bf16
  unsigned short* hsb = (unsigned short*)(ws + 3 * WMAT);   // [T][H] bf16
  // res aliases w1t: dead after gemm0_w2t completes (stream-ordered).
  unsigned short* res = w1t;                                // [NPAIR][H] bf16 (16MB)
  char* small = ws + 3 * WMAT + (size_t)T_TOK * H_DIM * 2;
  int* eid = (int*)small;                          // NPAIR
  float* wgt = (float*)(small + NPAIR * 4);        // NPAIR
  int* rowmap = (int*)(small + 2 * NPAIR * 4);     // NPAIR
  int* posmap = (int*)(small + 3 * NPAIR * 4);     // NPAIR
  int* counts = (int*)(small + 4 * NPAIR * 4);     // 8
  int* fill = counts + 8;                          // 8

  hipMemsetAsync(counts, 0, 16 * sizeof(int), stream);

  prep1_kernel<<<256 + WT_NB, 256, 0, stream>>>(w1, hs, gw, w1t, hsb, eid, wgt, counts);
  scatter_kernel<<<NPAIR / 256, 256, 0, stream>>>(eid, counts, fill, rowmap, posmap);

  gemm0_w2t_kernel<<<G0_NWG + WT_NB, 256, 0, stream>>>(
      hsb, w1t, act, w2, w2t, counts, rowmap);
  moe_gemm1<<<MAX_RT * (H_DIM / BN), 256, 0, stream>>>(
      w2t, act, res, counts, rowmap, wgt);

  combine_kernel<<<T_TOK, 256, 0, stream>>>(res, posmap, out);
}

// Round 23
// 237.567 us; speedup vs baseline: 5.1122x; 1.0178x over previous
//
#include <hip/hip_runtime.h>
#include <hip/hip_bf16.h>

// ---------------- problem constants (match setup_inputs) ----------------
#define T_TOK 4096
#define H_DIM 1024
#define E_NUM 8
#define I_DIM 3584
#define NPAIR (T_TOK * 2)   // top_k = 2
#define MAX_RT 72           // worst-case total row tiles: sum ceil(cnt_e/128) <= 64+7

#define BM 128
#define BN 128
#define BK 64
#define G0_NWG (MAX_RT * (I_DIM / BN))   // 2016 gemm0 blocks
#define WT_NB 3584                       // dual-tile transpose blocks per matrix

typedef __attribute__((ext_vector_type(8))) short bf16x8;
typedef __attribute__((ext_vector_type(4))) float f32x4;
typedef __attribute__((ext_vector_type(8))) unsigned short ushort8_t;
typedef __attribute__((ext_vector_type(4))) unsigned short ushort4_t;

// RNE fp32 -> bf16
__device__ __forceinline__ unsigned short f2bf(float x) {
  unsigned int u = __float_as_uint(x);
  unsigned int r = (u + 0x7FFFu + ((u >> 16) & 1u)) >> 16;
  return (unsigned short)r;
}
__device__ __forceinline__ float bf2f(unsigned short u) {
  return __uint_as_float((unsigned int)u << 16);
}

// async 16B global -> LDS (dest: wave-uniform base, HW adds lane*16)
__device__ __forceinline__ void gload16(const void* g, unsigned short* l) {
  __builtin_amdgcn_global_load_lds(
      (const __attribute__((address_space(1))) void*)g,
      (__attribute__((address_space(3))) void*)l, 16, 0, 0);
}

// ---------------- dual-tile transpose (2x 64-row passes, fused 256B writes) -
__device__ __forceinline__ void transpose_body2(const float* __restrict__ src,
                                                unsigned short* __restrict__ dst,
                                                int R, int C, int e, int c0, int r0,
                                                char* smem) {
  float (*tile)[65] = reinterpret_cast<float (*)[65]>(smem);
  const float* s = src + (size_t)e * R * C;
  unsigned short* d = dst + (size_t)e * R * C;
  const int th = threadIdx.x;
  const int tr = th >> 4;
  const int tc4 = (th & 15) * 4;
  const int wc = th >> 3;
  const int wr = (th & 7) * 8;
  ushort8_t oA[2];
#pragma unroll
  for (int it = 0; it < 4; ++it) {
    const int r = it * 16 + tr;
    float4 v = *reinterpret_cast<const float4*>(s + (size_t)(r0 + r) * C + c0 + tc4);
    tile[r][tc4] = v.x; tile[r][tc4 + 1] = v.y; tile[r][tc4 + 2] = v.z; tile[r][tc4 + 3] = v.w;
  }
  __syncthreads();
#pragma unroll
  for (int it = 0; it < 2; ++it) {
    const int c = it * 32 + wc;
#pragma unroll
    for (int j = 0; j < 8; ++j) oA[it][j] = f2bf(tile[wr + j][c]);
  }
  __syncthreads();
#pragma unroll
  for (int it = 0; it < 4; ++it) {
    const int r = it * 16 + tr;
    float4 v = *reinterpret_cast<const float4*>(s + (size_t)(r0 + 64 + r) * C + c0 + tc4);
    tile[r][tc4] = v.x; tile[r][tc4 + 1] = v.y; tile[r][tc4 + 2] = v.z; tile[r][tc4 + 3] = v.w;
  }
  __syncthreads();
#pragma unroll
  for (int it = 0; it < 2; ++it) {
    const int c = it * 32 + wc;
    ushort8_t oB;
#pragma unroll
    for (int j = 0; j < 8; ++j) oB[j] = f2bf(tile[wr + j][c]);
    *reinterpret_cast<ushort8_t*>(d + (size_t)(c0 + c) * R + r0 + wr) = oA[it];
    *reinterpret_cast<ushort8_t*>(d + (size_t)(c0 + c) * R + r0 + 64 + wr) = oB;
  }
}

__device__ __forceinline__ void router_body(const float* __restrict__ hs,
                                            const float* __restrict__ gw,
                                            unsigned short* __restrict__ hsb,
                                            int* __restrict__ eid, float* __restrict__ wgt,
                                            int* __restrict__ counts, int rbid, char* smem) {
  float* s_gw = reinterpret_cast<float*>(smem);          // 32 KB
  int* s_cnt = reinterpret_cast<int*>(smem + 32768);     // 32 B
  const int th = threadIdx.x;
  for (int u = th; u < 2048; u += 256) {
    const f32x4 v = *reinterpret_cast<const f32x4*>(gw + u * 4);
    *reinterpret_cast<f32x4*>(&s_gw[(u ^ ((u >> 3) & 7)) * 4]) = v;
  }
  if (th < E_NUM) s_cnt[th] = 0;
  __syncthreads();

  const int l = th & 63, w = th >> 6;
#pragma unroll 1
  for (int tt = 0; tt < 4; ++tt) {
    const int t = rbid * 16 + w * 4 + tt;
    const float* hrow = hs + (size_t)t * H_DIM;
    unsigned short* brow = hsb + (size_t)t * H_DIM;
    float acc[E_NUM];
#pragma unroll
    for (int e = 0; e < E_NUM; ++e) acc[e] = 0.f;
#pragma unroll
    for (int i = 0; i < 4; ++i) {
      const int h0 = i * 256 + l * 4;
      const f32x4 x = *reinterpret_cast<const f32x4*>(hrow + h0);
      ushort4_t o = { f2bf(x[0]), f2bf(x[1]), f2bf(x[2]), f2bf(x[3]) };
      *reinterpret_cast<ushort4_t*>(brow + h0) = o;
#pragma unroll
      for (int j = 0; j < 4; ++j) {
        const int h = h0 + j;
        const int p0 = (h * 2) ^ ((h >> 2) & 7);
        const f32x4 g0 = *reinterpret_cast<const f32x4*>(&s_gw[p0 * 4]);
        const f32x4 g1 = *reinterpret_cast<const f32x4*>(&s_gw[(p0 ^ 1) * 4]);
        acc[0] += x[j] * g0[0]; acc[1] += x[j] * g0[1];
        acc[2] += x[j] * g0[2]; acc[3] += x[j] * g0[3];
        acc[4] += x[j] * g1[0]; acc[5] += x[j] * g1[1];
        acc[6] += x[j] * g1[2]; acc[7] += x[j] * g1[3];
      }
    }
#pragma unroll
    for (int e = 0; e < E_NUM; ++e) {
#pragma unroll
      for (int off = 1; off < 64; off <<= 1) acc[e] += __shfl_xor(acc[e], off);
    }
    if (l == 0) {
      int i1 = 0;
#pragma unroll
      for (int e = 1; e < E_NUM; ++e) if (acc[e] > acc[i1]) i1 = e;
      int i2 = (i1 == 0) ? 1 : 0;
#pragma unroll
      for (int e = 0; e < E_NUM; ++e) if (e != i1 && acc[e] > acc[i2]) i2 = e;
      const float e2 = __expf(acc[i2] - acc[i1]);
      const float inv = 1.f / (1.f + e2);
      eid[t * 2] = i1;     wgt[t * 2] = inv;
      eid[t * 2 + 1] = i2; wgt[t * 2 + 1] = e2 * inv;
      atomicAdd(&s_cnt[i1], 1);
      atomicAdd(&s_cnt[i2], 1);
    }
  }
  __syncthreads();
  if (th < E_NUM && s_cnt[th] > 0) atomicAdd(&counts[th], s_cnt[th]);
}

// ---- kernel1: router (bids 0..255) + w1 dual-transpose (256..3839) --------
__global__ __launch_bounds__(256) void prep1_kernel(
    const float* __restrict__ w1, const float* __restrict__ hs,
    const float* __restrict__ gw,
    unsigned short* __restrict__ w1t, unsigned short* __restrict__ hsb,
    int* __restrict__ eid, float* __restrict__ wgt, int* __restrict__ counts) {
  __shared__ char smem[33024];   // router: 32KB+32B; transpose: 16.6KB
  const int bid = blockIdx.x;
  if (bid < 256) {
    router_body(hs, gw, hsb, eid, wgt, counts, bid, smem);
    return;
  }
  const int idx = bid - 256;     // w1: R=1024, C=3584; 56c x 8 row-pairs per e
  const int e = idx / 448, rem = idx % 448;
  transpose_body2(w1, w1t, H_DIM, I_DIM, e, (rem % 56) * 64, (rem / 56) * 128, smem);
}

// ---------------- scatter: block-local histogram + range reservation -------
__global__ void scatter_kernel(const int* __restrict__ eid, const int* __restrict__ counts,
                               int* __restrict__ fill, int* __restrict__ rowmap,
                               int* __restrict__ posmap) {
  __shared__ int hist[E_NUM], base[E_NUM];
  const int th = threadIdx.x;
  const int p = blockIdx.x * 256 + th;
  if (th < E_NUM) hist[th] = 0;
  __syncthreads();
  const int e = eid[p];
  const int rloc = atomicAdd(&hist[e], 1);
  __syncthreads();
  if (th < E_NUM) base[th] = (hist[th] > 0) ? atomicAdd(&fill[th], hist[th]) : 0;
  __syncthreads();
  int off = 0;
#pragma unroll
  for (int i = 0; i < E_NUM; ++i) off += (i < e) ? counts[i] : 0;
  const int pos = off + base[e] + rloc;
  rowmap[pos] = p;
  posmap[p] = pos;
}

// ------- combine: out[t] = res_bf16[pos(2t)] + res_bf16[pos(2t+1)] ---------
__global__ void combine_kernel(const unsigned short* __restrict__ res,
                               const int* __restrict__ posmap,
                               float* __restrict__ out) {
  const int t = blockIdx.x;
  const int th = threadIdx.x;
  const ushort4_t va = *reinterpret_cast<const ushort4_t*>(
      res + (size_t)posmap[t * 2] * H_DIM + th * 4);
  const ushort4_t vb = *reinterpret_cast<const ushort4_t*>(
      res + (size_t)posmap[t * 2 + 1] * H_DIM + th * 4);
  float4 o = { bf2f(va[0]) + bf2f(vb[0]), bf2f(va[1]) + bf2f(vb[1]),
               bf2f(va[2]) + bf2f(vb[2]), bf2f(va[3]) + bf2f(vb[3]) };
  *reinterpret_cast<float4*>(out + (size_t)t * H_DIM + th * 4) = o;
}

// ---- kernel2: gemm0 (bids 0..2015, supertiled) + w2 dual-transpose --------
// gemm0 is latency-bound (25% MfmaUtil, 1.4 TB/s): w2t blocks soak idle BW.
__global__ __launch_bounds__(256, 4) void gemm0_w2t_kernel(
    const unsigned short* __restrict__ hsb, const unsigned short* __restrict__ w1t,
    unsigned short* __restrict__ act,
    const float* __restrict__ w2, unsigned short* __restrict__ w2t,
    const int* __restrict__ counts, const int* __restrict__ rowmap) {
  __shared__ char smem[(BM * BK + BN * BK) * 2];   // 32 KB
  const int bid = blockIdx.x;
  if (bid >= G0_NWG) {
    const int idx = bid - G0_NWG;  // w2: R=3584, C=1024; 16c x 28 row-pairs per e
    const int e = idx / 448, rem = idx % 448;
    transpose_body2(w2, w2t, I_DIM, H_DIM, e, (rem % 16) * 64, (rem / 16) * 128, smem);
    return;
  }
  unsigned short* As = reinterpret_cast<unsigned short*>(smem);
  unsigned short* Bs = As + BM * BK;

  // T1 bijective XCD swizzle + 9rt x 4ct supertile (A 2.3MB + B 1MB in L2)
  constexpr int CHUNK = G0_NWG / 8;   // 252
  const int wgid = (bid & 7) * CHUNK + (bid >> 3);
  const int l = wgid % CHUNK;
  const int sg = l / 36;
  const int q = l % 36;
  const int rt = (wgid / CHUNK) * 9 + q % 9;
  const int ct = sg * 4 + q / 9;

  // expert walk from counts (prefix on the fly)
  int e = -1, loc_rt = 0, off_e = 0, cnt = 0;
  {
    int acc_t = 0, off = 0;
#pragma unroll
    for (int ee = 0; ee < E_NUM; ++ee) {
      const int c = counts[ee];
      const int nt = (c + BM - 1) >> 7;
      if (e < 0 && rt < acc_t + nt) { e = ee; loc_rt = rt - acc_t; off_e = off; cnt = c; }
      acc_t += nt; off += c;
    }
  }
  if (e < 0) return;

  const int cnt_local = min(BM, cnt - loc_rt * BM);
  const int r_base = off_e + loc_rt * BM;
  const int th = threadIdx.x;
  const int lane = th & 63, wid = th >> 6;

  const int n0 = ct * BN;
  const unsigned short* wbase = w1t + (size_t)e * ((size_t)I_DIM * H_DIM) + (size_t)n0 * H_DIM;

  // staging: LDS dest linear; source chunk pre-swizzled: cg = (lane&7)^(row&7)
  const int srow = lane >> 3;
  const int cg = (lane & 7) ^ srow;
  const char* aptr[4];
  const char* bptr[4];
#pragma unroll
  for (int i = 0; i < 4; ++i) {
    const int r = i * 32 + wid * 8 + srow;
    const int rr = (r < cnt_local) ? r : (cnt_local - 1);
    const int tok = rowmap[off_e + loc_rt * BM + rr] >> 1;
    aptr[i] = (const char*)(hsb + (size_t)tok * H_DIM) + cg * 16;
    bptr[i] = (const char*)(wbase + (size_t)r * H_DIM) + cg * 16;
  }
  unsigned short* dstA[4];
  unsigned short* dstB[4];
#pragma unroll
  for (int i = 0; i < 4; ++i) {
    dstA[i] = &As[(i * 32 + wid * 8) * BK];   // wave-uniform
    dstB[i] = &Bs[(i * 32 + wid * 8) * BK];
  }

  f32x4 acc[4][4];
#pragma unroll
  for (int m = 0; m < 4; ++m)
#pragma unroll
    for (int n = 0; n < 4; ++n) acc[m][n] = (f32x4){0.f, 0.f, 0.f, 0.f};

  const int wm = (wid >> 1) * 64;
  const int wn = (wid & 1) * 64;
  const int fr = lane & 15;
  const int fq = lane >> 4;
  const int sxor = fr & 7;

  for (int k0 = 0; k0 < H_DIM; k0 += BK) {
    const int kb = k0 * 2;
#pragma unroll
    for (int i = 0; i < 4; ++i) gload16(aptr[i] + kb, dstA[i]);
#pragma unroll
    for (int i = 0; i < 4; ++i) gload16(bptr[i] + kb, dstB[i]);
    __syncthreads();   // drains vmcnt before s_barrier

#pragma unroll
    for (int kk = 0; kk < 2; ++kk) {
      bf16x8 af[4], bf[4];
#pragma unroll
      for (int m = 0; m < 4; ++m)
        af[m] = *reinterpret_cast<const bf16x8*>(
            &As[(wm + m * 16 + fr) * BK + ((kk * 4 + fq) ^ sxor) * 8]);
#pragma unroll
      for (int n = 0; n < 4; ++n)
        bf[n] = *reinterpret_cast<const bf16x8*>(
            &Bs[(wn + n * 16 + fr) * BK + ((kk * 4 + fq) ^ sxor) * 8]);
#pragma unroll
      for (int m = 0; m < 4; ++m)
#pragma unroll
        for (int n = 0; n < 4; ++n)
          acc[m][n] = __builtin_amdgcn_mfma_f32_16x16x32_bf16(af[m], bf[n], acc[m][n], 0, 0, 0);
    }
    __syncthreads();
  }

  // ---- epilogue: silu -> act bf16
#pragma unroll
  for (int m = 0; m < 4; ++m) {
    const int row = wm + m * 16 + fq * 4;
#pragma unroll
    for (int n = 0; n < 4; ++n) {
      const int col = wn + n * 16 + fr;
#pragma unroll
      for (int r = 0; r < 4; ++r) {
        const int rw = row + r;
        if (rw < cnt_local) {
          const float x = acc[m][n][r];
          const float s = x / (1.f + __expf(-x));
          act[(size_t)(r_base + rw) * I_DIM + n0 + col] = f2bf(s);
        }
      }
    }
  }
}

// -------- gemm1 (128x128, 3rt x 2ct supertiles, bf16 res stores) -----------
__launch_bounds__(256, 4)
__global__ void moe_gemm1(const unsigned short* __restrict__ w2t,
                          const unsigned short* __restrict__ act_in,
                          unsigned short* __restrict__ res,
                          const int* __restrict__ counts,
                          const int* __restrict__ rowmap,
                          const float* __restrict__ wgt) {
  constexpr int NCT = H_DIM / BN;            // 8
  constexpr int NWG = MAX_RT * NCT;          // 576
  constexpr int CHUNK = NWG / 8;             // 72

  __shared__ unsigned short As[BM * BK];
  __shared__ unsigned short Bs[BN * BK];
  __shared__ float s_w[BM];

  // T1 bijective XCD swizzle; 3rt x 2ct supertiles within each 72-wgid chunk
  // (A 2.7MB + B 1.8MB ~ L2-resident vs old band's 9.1MB). Walk rt-group-
  // major so consecutive supertiles keep the B ct-pair resident.
  const int bid = blockIdx.x;
  const int wgid = (bid & 7) * CHUNK + (bid >> 3);
  int rt, ct;
  {
    const int c9 = (wgid / CHUNK) * 9;
    const int l = wgid % CHUNK;
    const int s = l / 6, i = l % 6;
    rt = c9 + (s % 3) * 3 + (i % 3);
    ct = (s / 3) * 2 + (i / 3);
  }

  // expert walk from counts (prefix on the fly)
  int e = -1, loc_rt = 0, off_e = 0, cnt = 0;
  {
    int acc_t = 0, off = 0;
#pragma unroll
    for (int ee = 0; ee < E_NUM; ++ee) {
      const int c = counts[ee];
      const int nt = (c + BM - 1) >> 7;
      if (e < 0 && rt < acc_t + nt) { e = ee; loc_rt = rt - acc_t; off_e = off; cnt = c; }
      acc_t += nt; off += c;
    }
  }
  if (e < 0) return;

  const int cnt_local = min(BM, cnt - loc_rt * BM);
  const int r_base = off_e + loc_rt * BM;
  const int th = threadIdx.x;
  const int lane = th & 63, wid = th >> 6;

  if (th < BM) {
    int r = loc_rt * BM + th;
    if (r >= cnt) r = cnt - 1;
    s_w[th] = wgt[rowmap[off_e + r]];
  }

  const int n0 = ct * BN;
  const unsigned short* wbase = w2t + (size_t)e * ((size_t)I_DIM * H_DIM) + (size_t)n0 * I_DIM;

  const int srow = lane >> 3;
  const int cg = (lane & 7) ^ srow;
  const char* aptr[4];
  const char* bptr[4];
#pragma unroll
  for (int i = 0; i < 4; ++i) {
    const int r = i * 32 + wid * 8 + srow;
    const int rr = (r < cnt_local) ? r : (cnt_local - 1);
    aptr[i] = (const char*)(act_in + (size_t)(r_base + rr) * I_DIM) + cg * 16;
    bptr[i] = (const char*)(wbase + (size_t)r * I_DIM) + cg * 16;
  }
  unsigned short* dstA[4];
  unsigned short* dstB[4];
#pragma unroll
  for (int i = 0; i < 4; ++i) {
    dstA[i] = &As[(i * 32 + wid * 8) * BK];
    dstB[i] = &Bs[(i * 32 + wid * 8) * BK];
  }

  f32x4 acc[4][4];
#pragma unroll
  for (int m = 0; m < 4; ++m)
#pragma unroll
    for (int n = 0; n < 4; ++n) acc[m][n] = (f32x4){0.f, 0.f, 0.f, 0.f};

  const int wm = (wid >> 1) * 64;
  const int wn = (wid & 1) * 64;
  const int fr = lane & 15;
  const int fq = lane >> 4;
  const int sxor = fr & 7;

  for (int k0 = 0; k0 < I_DIM; k0 += BK) {
    const int kb = k0 * 2;
#pragma unroll
    for (int i = 0; i < 4; ++i) gload16(aptr[i] + kb, dstA[i]);
#pragma unroll
    for (int i = 0; i < 4; ++i) gload16(bptr[i] + kb, dstB[i]);
    __syncthreads();

#pragma unroll
    for (int kk = 0; kk < 2; ++kk) {
      bf16x8 af[4], bf[4];
#pragma unroll
      for (int m = 0; m < 4; ++m)
        af[m] = *reinterpret_cast<const bf16x8*>(
            &As[(wm + m * 16 + fr) * BK + ((kk * 4 + fq) ^ sxor) * 8]);
#pragma unroll
      for (int n = 0; n < 4; ++n)
        bf[n] = *reinterpret_cast<const bf16x8*>(
            &Bs[(wn + n * 16 + fr) * BK + ((kk * 4 + fq) ^ sxor) * 8]);
#pragma unroll
      for (int m = 0; m < 4; ++m)
#pragma unroll
        for (int n = 0; n < 4; ++n)
          acc[m][n] = __builtin_amdgcn_mfma_f32_16x16x32_bf16(af[m], bf[n], acc[m][n], 0, 0, 0);
    }
    __syncthreads();
  }

#pragma unroll
  for (int m = 0; m < 4; ++m) {
    const int row = wm + m * 16 + fq * 4;
#pragma unroll
    for (int n = 0; n < 4; ++n) {
      const int col = wn + n * 16 + fr;
#pragma unroll
      for (int r = 0; r < 4; ++r) {
        const int rw = row + r;
        if (rw < cnt_local)
          res[(size_t)(r_base + rw) * H_DIM + n0 + col] = f2bf(acc[m][n][r] * s_w[rw]);
      }
    }
  }
}

// ---------------- launch ----------------
extern "C" void kernel_launch(void* const* d_in, const int* in_sizes, int n_in,
                              void* d_out, int out_size, void* d_ws, size_t ws_size,
                              hipStream_t stream) {
  const float* hs = (const float*)d_in[0];
  const float* gw = (const float*)d_in[1];
  const float* w1 = (const float*)d_in[2];
  const float* w2 = (const float*)d_in[3];
  float* out = (float*)d_out;

  char* ws = (char*)d_ws;
  const size_t WMAT = (size_t)E_NUM * I_DIM * H_DIM * 2;   // 58,720,256 B
  unsigned short* w1t = (unsigned short*)ws;                // [E][I][H] bf16
  unsigned short* w2t = (unsigned short*)(ws + WMAT);       // [E][H][I] bf16
  unsigned short* act = (unsigned short*)(ws + 2 * WMAT);   // [NPAIR][I] bf16
  unsigned short* hsb = (unsigned short*)(ws + 3 * WMAT);   // [T][H] bf16
  // res aliases w1t: dead after gemm0_w2t completes (stream-ordered).
  unsigned short* res = w1t;                                // [NPAIR][H] bf16 (16MB)
  char* small = ws + 3 * WMAT + (size_t)T_TOK * H_DIM * 2;
  int* eid = (int*)small;                          // NPAIR
  float* wgt = (float*)(small + NPAIR * 4);        // NPAIR
  int* rowmap = (int*)(small + 2 * NPAIR * 4);     // NPAIR
  int* posmap = (int*)(small + 3 * NPAIR * 4);     // NPAIR
  int* counts = (int*)(small + 4 * NPAIR * 4);     // 8
  int* fill = counts + 8;                          // 8

  hipMemsetAsync(counts, 0, 16 * sizeof(int), stream);

  prep1_kernel<<<256 + WT_NB, 256, 0, stream>>>(w1, hs, gw, w1t, hsb, eid, wgt, counts);
  scatter_kernel<<<NPAIR / 256, 256, 0, stream>>>(eid, counts, fill, rowmap, posmap);

  gemm0_w2t_kernel<<<G0_NWG + WT_NB, 256, 0, stream>>>(
      hsb, w1t, act, w2, w2t, counts, rowmap);
  moe_gemm1<<<MAX_RT * (H_DIM / BN), 256, 0, stream>>>(
      w2t, act, res, counts, rowmap, wgt);

  combine_kernel<<<T_TOK, 256, 0, stream>>>(res, posmap, out);
}

// Round 24
// 237.120 us; speedup vs baseline: 5.1219x; 1.0019x over previous
//
#include <hip/hip_runtime.h>
#include <hip/hip_bf16.h>

// ---------------- problem constants (match setup_inputs) ----------------
#define T_TOK 4096
#define H_DIM 1024
#define E_NUM 8
#define I_DIM 3584
#define NPAIR (T_TOK * 2)   // top_k = 2
#define MAX_RT 72           // worst-case total row tiles: sum ceil(cnt_e/128) <= 64+7

#define BM 128
#define BN 128
#define BK 64
#define G0_NWG (MAX_RT * (I_DIM / BN))   // 2016 gemm0 blocks
#define WT_NB 3584                       // dual-tile transpose blocks per matrix

typedef __attribute__((ext_vector_type(8))) short bf16x8;
typedef __attribute__((ext_vector_type(4))) float f32x4;
typedef __attribute__((ext_vector_type(8))) unsigned short ushort8_t;
typedef __attribute__((ext_vector_type(4))) unsigned short ushort4_t;

// RNE fp32 -> bf16
__device__ __forceinline__ unsigned short f2bf(float x) {
  unsigned int u = __float_as_uint(x);
  unsigned int r = (u + 0x7FFFu + ((u >> 16) & 1u)) >> 16;
  return (unsigned short)r;
}
__device__ __forceinline__ float bf2f(unsigned short u) {
  return __uint_as_float((unsigned int)u << 16);
}

// async 16B global -> LDS (dest: wave-uniform base, HW adds lane*16)
__device__ __forceinline__ void gload16(const void* g, unsigned short* l) {
  __builtin_amdgcn_global_load_lds(
      (const __attribute__((address_space(1))) void*)g,
      (__attribute__((address_space(3))) void*)l, 16, 0, 0);
}

// ---------------- dual-tile transpose (2x 64-row passes, fused 256B writes) -
__device__ __forceinline__ void transpose_body2(const float* __restrict__ src,
                                                unsigned short* __restrict__ dst,
                                                int R, int C, int e, int c0, int r0,
                                                char* smem) {
  float (*tile)[65] = reinterpret_cast<float (*)[65]>(smem);
  const float* s = src + (size_t)e * R * C;
  unsigned short* d = dst + (size_t)e * R * C;
  const int th = threadIdx.x;
  const int tr = th >> 4;
  const int tc4 = (th & 15) * 4;
  const int wc = th >> 3;
  const int wr = (th & 7) * 8;
  ushort8_t oA[2];
#pragma unroll
  for (int it = 0; it < 4; ++it) {
    const int r = it * 16 + tr;
    float4 v = *reinterpret_cast<const float4*>(s + (size_t)(r0 + r) * C + c0 + tc4);
    tile[r][tc4] = v.x; tile[r][tc4 + 1] = v.y; tile[r][tc4 + 2] = v.z; tile[r][tc4 + 3] = v.w;
  }
  __syncthreads();
#pragma unroll
  for (int it = 0; it < 2; ++it) {
    const int c = it * 32 + wc;
#pragma unroll
    for (int j = 0; j < 8; ++j) oA[it][j] = f2bf(tile[wr + j][c]);
  }
  __syncthreads();
#pragma unroll
  for (int it = 0; it < 4; ++it) {
    const int r = it * 16 + tr;
    float4 v = *reinterpret_cast<const float4*>(s + (size_t)(r0 + 64 + r) * C + c0 + tc4);
    tile[r][tc4] = v.x; tile[r][tc4 + 1] = v.y; tile[r][tc4 + 2] = v.z; tile[r][tc4 + 3] = v.w;
  }
  __syncthreads();
#pragma unroll
  for (int it = 0; it < 2; ++it) {
    const int c = it * 32 + wc;
    ushort8_t oB;
#pragma unroll
    for (int j = 0; j < 8; ++j) oB[j] = f2bf(tile[wr + j][c]);
    *reinterpret_cast<ushort8_t*>(d + (size_t)(c0 + c) * R + r0 + wr) = oA[it];
    *reinterpret_cast<ushort8_t*>(d + (size_t)(c0 + c) * R + r0 + 64 + wr) = oB;
  }
}

__device__ __forceinline__ void router_body(const float* __restrict__ hs,
                                            const float* __restrict__ gw,
                                            unsigned short* __restrict__ hsb,
                                            int* __restrict__ eid, float* __restrict__ wgt,
                                            int* __restrict__ counts, int rbid, char* smem) {
  float* s_gw = reinterpret_cast<float*>(smem);          // 32 KB
  int* s_cnt = reinterpret_cast<int*>(smem + 32768);     // 32 B
  const int th = threadIdx.x;
  for (int u = th; u < 2048; u += 256) {
    const f32x4 v = *reinterpret_cast<const f32x4*>(gw + u * 4);
    *reinterpret_cast<f32x4*>(&s_gw[(u ^ ((u >> 3) & 7)) * 4]) = v;
  }
  if (th < E_NUM) s_cnt[th] = 0;
  __syncthreads();

  const int l = th & 63, w = th >> 6;
#pragma unroll 1
  for (int tt = 0; tt < 4; ++tt) {
    const int t = rbid * 16 + w * 4 + tt;
    const float* hrow = hs + (size_t)t * H_DIM;
    unsigned short* brow = hsb + (size_t)t * H_DIM;
    float acc[E_NUM];
#pragma unroll
    for (int e = 0; e < E_NUM; ++e) acc[e] = 0.f;
#pragma unroll
    for (int i = 0; i < 4; ++i) {
      const int h0 = i * 256 + l * 4;
      const f32x4 x = *reinterpret_cast<const f32x4*>(hrow + h0);
      ushort4_t o = { f2bf(x[0]), f2bf(x[1]), f2bf(x[2]), f2bf(x[3]) };
      *reinterpret_cast<ushort4_t*>(brow + h0) = o;
#pragma unroll
      for (int j = 0; j < 4; ++j) {
        const int h = h0 + j;
        const int p0 = (h * 2) ^ ((h >> 2) & 7);
        const f32x4 g0 = *reinterpret_cast<const f32x4*>(&s_gw[p0 * 4]);
        const f32x4 g1 = *reinterpret_cast<const f32x4*>(&s_gw[(p0 ^ 1) * 4]);
        acc[0] += x[j] * g0[0]; acc[1] += x[j] * g0[1];
        acc[2] += x[j] * g0[2]; acc[3] += x[j] * g0[3];
        acc[4] += x[j] * g1[0]; acc[5] += x[j] * g1[1];
        acc[6] += x[j] * g1[2]; acc[7] += x[j] * g1[3];
      }
    }
#pragma unroll
    for (int e = 0; e < E_NUM; ++e) {
#pragma unroll
      for (int off = 1; off < 64; off <<= 1) acc[e] += __shfl_xor(acc[e], off);
    }
    if (l == 0) {
      int i1 = 0;
#pragma unroll
      for (int e = 1; e < E_NUM; ++e) if (acc[e] > acc[i1]) i1 = e;
      int i2 = (i1 == 0) ? 1 : 0;
#pragma unroll
      for (int e = 0; e < E_NUM; ++e) if (e != i1 && acc[e] > acc[i2]) i2 = e;
      const float e2 = __expf(acc[i2] - acc[i1]);
      const float inv = 1.f / (1.f + e2);
      eid[t * 2] = i1;     wgt[t * 2] = inv;
      eid[t * 2 + 1] = i2; wgt[t * 2 + 1] = e2 * inv;
      atomicAdd(&s_cnt[i1], 1);
      atomicAdd(&s_cnt[i2], 1);
    }
  }
  __syncthreads();
  if (th < E_NUM && s_cnt[th] > 0) atomicAdd(&counts[th], s_cnt[th]);
}

// ---- kernel1: router (bids 0..255) + w1 dual-transpose (256..3839) --------
__global__ __launch_bounds__(256) void prep1_kernel(
    const float* __restrict__ w1, const float* __restrict__ hs,
    const float* __restrict__ gw,
    unsigned short* __restrict__ w1t, unsigned short* __restrict__ hsb,
    int* __restrict__ eid, float* __restrict__ wgt, int* __restrict__ counts) {
  __shared__ char smem[33024];   // router: 32KB+32B; transpose: 16.6KB
  const int bid = blockIdx.x;
  if (bid < 256) {
    router_body(hs, gw, hsb, eid, wgt, counts, bid, smem);
    return;
  }
  const int idx = bid - 256;     // w1: R=1024, C=3584; 56c x 8 row-pairs per e
  const int e = idx / 448, rem = idx % 448;
  transpose_body2(w1, w1t, H_DIM, I_DIM, e, (rem % 56) * 64, (rem / 56) * 128, smem);
}

// ---------------- scatter: block-local histogram + range reservation -------
__global__ void scatter_kernel(const int* __restrict__ eid, const int* __restrict__ counts,
                               int* __restrict__ fill, int* __restrict__ rowmap,
                               int* __restrict__ posmap) {
  __shared__ int hist[E_NUM], base[E_NUM];
  const int th = threadIdx.x;
  const int p = blockIdx.x * 256 + th;
  if (th < E_NUM) hist[th] = 0;
  __syncthreads();
  const int e = eid[p];
  const int rloc = atomicAdd(&hist[e], 1);
  __syncthreads();
  if (th < E_NUM) base[th] = (hist[th] > 0) ? atomicAdd(&fill[th], hist[th]) : 0;
  __syncthreads();
  int off = 0;
#pragma unroll
  for (int i = 0; i < E_NUM; ++i) off += (i < e) ? counts[i] : 0;
  const int pos = off + base[e] + rloc;
  rowmap[pos] = p;
  posmap[p] = pos;
}

// ------- combine: out[t] = res_bf16[pos(2t)] + res_bf16[pos(2t+1)] ---------
__global__ void combine_kernel(const unsigned short* __restrict__ res,
                               const int* __restrict__ posmap,
                               float* __restrict__ out) {
  const int t = blockIdx.x;
  const int th = threadIdx.x;
  const ushort4_t va = *reinterpret_cast<const ushort4_t*>(
      res + (size_t)posmap[t * 2] * H_DIM + th * 4);
  const ushort4_t vb = *reinterpret_cast<const ushort4_t*>(
      res + (size_t)posmap[t * 2 + 1] * H_DIM + th * 4);
  float4 o = { bf2f(va[0]) + bf2f(vb[0]), bf2f(va[1]) + bf2f(vb[1]),
               bf2f(va[2]) + bf2f(vb[2]), bf2f(va[3]) + bf2f(vb[3]) };
  *reinterpret_cast<float4*>(out + (size_t)t * H_DIM + th * 4) = o;
}

// ---- kernel2: gemm0 (bids 0..2015, supertiled) + w2 dual-transpose --------
__global__ __launch_bounds__(256, 4) void gemm0_w2t_kernel(
    const unsigned short* __restrict__ hsb, const unsigned short* __restrict__ w1t,
    unsigned short* __restrict__ act,
    const float* __restrict__ w2, unsigned short* __restrict__ w2t,
    const int* __restrict__ counts, const int* __restrict__ rowmap) {
  __shared__ char smem[(BM * BK + BN * BK) * 2];   // 32 KB
  const int bid = blockIdx.x;
  if (bid >= G0_NWG) {
    const int idx = bid - G0_NWG;  // w2: R=3584, C=1024; 16c x 28 row-pairs per e
    const int e = idx / 448, rem = idx % 448;
    transpose_body2(w2, w2t, I_DIM, H_DIM, e, (rem % 16) * 64, (rem / 16) * 128, smem);
    return;
  }
  unsigned short* As = reinterpret_cast<unsigned short*>(smem);
  unsigned short* Bs = As + BM * BK;

  // T1 bijective XCD swizzle + 9rt x 4ct supertile (A 2.3MB + B 1MB in L2)
  constexpr int CHUNK = G0_NWG / 8;   // 252
  const int wgid = (bid & 7) * CHUNK + (bid >> 3);
  const int l = wgid % CHUNK;
  const int sg = l / 36;
  const int q = l % 36;
  const int rt = (wgid / CHUNK) * 9 + q % 9;
  const int ct = sg * 4 + q / 9;

  // expert walk from counts (prefix on the fly)
  int e = -1, loc_rt = 0, off_e = 0, cnt = 0;
  {
    int acc_t = 0, off = 0;
#pragma unroll
    for (int ee = 0; ee < E_NUM; ++ee) {
      const int c = counts[ee];
      const int nt = (c + BM - 1) >> 7;
      if (e < 0 && rt < acc_t + nt) { e = ee; loc_rt = rt - acc_t; off_e = off; cnt = c; }
      acc_t += nt; off += c;
    }
  }
  if (e < 0) return;

  const int cnt_local = min(BM, cnt - loc_rt * BM);
  const int r_base = off_e + loc_rt * BM;
  const int th = threadIdx.x;
  const int lane = th & 63, wid = th >> 6;

  const int n0 = ct * BN;
  const unsigned short* wbase = w1t + (size_t)e * ((size_t)I_DIM * H_DIM) + (size_t)n0 * H_DIM;

  // staging: LDS dest linear; source chunk pre-swizzled: cg = (lane&7)^(row&7)
  const int srow = lane >> 3;
  const int cg = (lane & 7) ^ srow;
  const char* aptr[4];
  const char* bptr[4];
#pragma unroll
  for (int i = 0; i < 4; ++i) {
    const int r = i * 32 + wid * 8 + srow;
    const int rr = (r < cnt_local) ? r : (cnt_local - 1);
    const int tok = rowmap[off_e + loc_rt * BM + rr] >> 1;
    aptr[i] = (const char*)(hsb + (size_t)tok * H_DIM) + cg * 16;
    bptr[i] = (const char*)(wbase + (size_t)r * H_DIM) + cg * 16;
  }
  unsigned short* dstA[4];
  unsigned short* dstB[4];
#pragma unroll
  for (int i = 0; i < 4; ++i) {
    dstA[i] = &As[(i * 32 + wid * 8) * BK];   // wave-uniform
    dstB[i] = &Bs[(i * 32 + wid * 8) * BK];
  }

  f32x4 acc[4][4];
#pragma unroll
  for (int m = 0; m < 4; ++m)
#pragma unroll
    for (int n = 0; n < 4; ++n) acc[m][n] = (f32x4){0.f, 0.f, 0.f, 0.f};

  const int wm = (wid >> 1) * 64;
  const int wn = (wid & 1) * 64;
  const int fr = lane & 15;
  const int fq = lane >> 4;
  const int sxor = fr & 7;

  for (int k0 = 0; k0 < H_DIM; k0 += BK) {
    const int kb = k0 * 2;
#pragma unroll
    for (int i = 0; i < 4; ++i) gload16(aptr[i] + kb, dstA[i]);
#pragma unroll
    for (int i = 0; i < 4; ++i) gload16(bptr[i] + kb, dstB[i]);
    __syncthreads();   // drains vmcnt before s_barrier

#pragma unroll
    for (int kk = 0; kk < 2; ++kk) {
      bf16x8 af[4], bf[4];
#pragma unroll
      for (int m = 0; m < 4; ++m)
        af[m] = *reinterpret_cast<const bf16x8*>(
            &As[(wm + m * 16 + fr) * BK + ((kk * 4 + fq) ^ sxor) * 8]);
#pragma unroll
      for (int n = 0; n < 4; ++n)
        bf[n] = *reinterpret_cast<const bf16x8*>(
            &Bs[(wn + n * 16 + fr) * BK + ((kk * 4 + fq) ^ sxor) * 8]);
#pragma unroll
      for (int m = 0; m < 4; ++m)
#pragma unroll
        for (int n = 0; n < 4; ++n)
          acc[m][n] = __builtin_amdgcn_mfma_f32_16x16x32_bf16(af[m], bf[n], acc[m][n], 0, 0, 0);
    }
    __syncthreads();
  }

  // ---- epilogue: silu -> act bf16
#pragma unroll
  for (int m = 0; m < 4; ++m) {
    const int row = wm + m * 16 + fq * 4;
#pragma unroll
    for (int n = 0; n < 4; ++n) {
      const int col = wn + n * 16 + fr;
#pragma unroll
      for (int r = 0; r < 4; ++r) {
        const int rw = row + r;
        if (rw < cnt_local) {
          const float x = acc[m][n][r];
          const float s = x / (1.f + __expf(-x));
          act[(size_t)(r_base + rw) * I_DIM + n0 + col] = f2bf(s);
        }
      }
    }
  }
}

// -------- gemm1 (128x128, 2rt x 2ct supertiles, bf16 res stores) -----------
__launch_bounds__(256, 4)
__global__ void moe_gemm1(const unsigned short* __restrict__ w2t,
                          const unsigned short* __restrict__ act_in,
                          unsigned short* __restrict__ res,
                          const int* __restrict__ counts,
                          const int* __restrict__ rowmap,
                          const float* __restrict__ wgt) {
  constexpr int NCT = H_DIM / BN;            // 8
  constexpr int NWG = MAX_RT * NCT;          // 576
  constexpr int CHUNK = NWG / 8;             // 72

  __shared__ unsigned short As[BM * BK];
  __shared__ unsigned short Bs[BN * BK];
  __shared__ float s_w[BM];

  // T1 bijective XCD swizzle; 2rt x 2ct supertiles (A 1.8MB + B 1.8MB, fully
  // L2-resident). Per ct-pair group (18 blocks): 4 supertiles + 1 tail rt,
  // so the B ct-pair is loaded once per 18-block group.
  const int bid = blockIdx.x;
  const int wgid = (bid & 7) * CHUNK + (bid >> 3);
  int rt, ct;
  {
    const int c9 = (wgid / CHUNK) * 9;
    const int l = wgid % CHUNK;
    const int ctp = l / 18;          // ct pair 0..3
    const int m = l % 18;
    if (m < 16) {
      const int st = m >> 2, i = m & 3;
      rt = c9 + st * 2 + (i & 1);
      ct = ctp * 2 + (i >> 1);
    } else {
      rt = c9 + 8;
      ct = ctp * 2 + (m - 16);
    }
  }

  // expert walk from counts (prefix on the fly)
  int e = -1, loc_rt = 0, off_e = 0, cnt = 0;
  {
    int acc_t = 0, off = 0;
#pragma unroll
    for (int ee = 0; ee < E_NUM; ++ee) {
      const int c = counts[ee];
      const int nt = (c + BM - 1) >> 7;
      if (e < 0 && rt < acc_t + nt) { e = ee; loc_rt = rt - acc_t; off_e = off; cnt = c; }
      acc_t += nt; off += c;
    }
  }
  if (e < 0) return;

  const int cnt_local = min(BM, cnt - loc_rt * BM);
  const int r_base = off_e + loc_rt * BM;
  const int th = threadIdx.x;
  const int lane = th & 63, wid = th >> 6;

  if (th < BM) {
    int r = loc_rt * BM + th;
    if (r >= cnt) r = cnt - 1;
    s_w[th] = wgt[rowmap[off_e + r]];
  }

  const int n0 = ct * BN;
  const unsigned short* wbase = w2t + (size_t)e * ((size_t)I_DIM * H_DIM) + (size_t)n0 * I_DIM;

  const int srow = lane >> 3;
  const int cg = (lane & 7) ^ srow;
  const char* aptr[4];
  const char* bptr[4];
#pragma unroll
  for (int i = 0; i < 4; ++i) {
    const int r = i * 32 + wid * 8 + srow;
    const int rr = (r < cnt_local) ? r : (cnt_local - 1);
    aptr[i] = (const char*)(act_in + (size_t)(r_base + rr) * I_DIM) + cg * 16;
    bptr[i] = (const char*)(wbase + (size_t)r * I_DIM) + cg * 16;
  }
  unsigned short* dstA[4];
  unsigned short* dstB[4];
#pragma unroll
  for (int i = 0; i < 4; ++i) {
    dstA[i] = &As[(i * 32 + wid * 8) * BK];
    dstB[i] = &Bs[(i * 32 + wid * 8) * BK];
  }

  f32x4 acc[4][4];
#pragma unroll
  for (int m = 0; m < 4; ++m)
#pragma unroll
    for (int n = 0; n < 4; ++n) acc[m][n] = (f32x4){0.f, 0.f, 0.f, 0.f};

  const int wm = (wid >> 1) * 64;
  const int wn = (wid & 1) * 64;
  const int fr = lane & 15;
  const int fq = lane >> 4;
  const int sxor = fr & 7;

  for (int k0 = 0; k0 < I_DIM; k0 += BK) {
    const int kb = k0 * 2;
#pragma unroll
    for (int i = 0; i < 4; ++i) gload16(aptr[i] + kb, dstA[i]);
#pragma unroll
    for (int i = 0; i < 4; ++i) gload16(bptr[i] + kb, dstB[i]);
    __syncthreads();

#pragma unroll
    for (int kk = 0; kk < 2; ++kk) {
      bf16x8 af[4], bf[4];
#pragma unroll
      for (int m = 0; m < 4; ++m)
        af[m] = *reinterpret_cast<const bf16x8*>(
            &As[(wm + m * 16 + fr) * BK + ((kk * 4 + fq) ^ sxor) * 8]);
#pragma unroll
      for (int n = 0; n < 4; ++n)
        bf[n] = *reinterpret_cast<const bf16x8*>(
            &Bs[(wn + n * 16 + fr) * BK + ((kk * 4 + fq) ^ sxor) * 8]);
#pragma unroll
      for (int m = 0; m < 4; ++m)
#pragma unroll
        for (int n = 0; n < 4; ++n)
          acc[m][n] = __builtin_amdgcn_mfma_f32_16x16x32_bf16(af[m], bf[n], acc[m][n], 0, 0, 0);
    }
    __syncthreads();
  }

#pragma unroll
  for (int m = 0; m < 4; ++m) {
    const int row = wm + m * 16 + fq * 4;
#pragma unroll
    for (int n = 0; n < 4; ++n) {
      const int col = wn + n * 16 + fr;
#pragma unroll
      for (int r = 0; r < 4; ++r) {
        const int rw = row + r;
        if (rw < cnt_local)
          res[(size_t)(r_base + rw) * H_DIM + n0 + col] = f2bf(acc[m][n][r] * s_w[rw]);
      }
    }
  }
}

// ---------------- launch ----------------
extern "C" void kernel_launch(void* const* d_in, const int* in_sizes, int n_in,
                              void* d_out, int out_size, void* d_ws, size_t ws_size,
                              hipStream_t stream) {
  const float* hs = (const float*)d_in[0];
  const float* gw = (const float*)d_in[1];
  const float* w1 = (const float*)d_in[2];
  const float* w2 = (const float*)d_in[3];
  float* out = (float*)d_out;

  char* ws = (char*)d_ws;
  const size_t WMAT = (size_t)E_NUM * I_DIM * H_DIM * 2;   // 58,720,256 B
  unsigned short* w1t = (unsigned short*)ws;                // [E][I][H] bf16
  unsigned short* w2t = (unsigned short*)(ws + WMAT);       // [E][H][I] bf16
  unsigned short* act = (unsigned short*)(ws + 2 * WMAT);   // [NPAIR][I] bf16
  unsigned short* hsb = (unsigned short*)(ws + 3 * WMAT);   // [T][H] bf16
  // res aliases w1t: dead after gemm0_w2t completes (stream-ordered).
  unsigned short* res = w1t;                                // [NPAIR][H] bf16 (16MB)
  char* small = ws + 3 * WMAT + (size_t)T_TOK * H_DIM * 2;
  int* eid = (int*)small;                          // NPAIR
  float* wgt = (float*)(small + NPAIR * 4);        // NPAIR
  int* rowmap = (int*)(small + 2 * NPAIR * 4);     // NPAIR
  int* posmap = (int*)(small + 3 * NPAIR * 4);     // NPAIR
  int* counts = (int*)(small + 4 * NPAIR * 4);     // 8
  int* fill = counts + 8;                          // 8

  hipMemsetAsync(counts, 0, 16 * sizeof(int), stream);

  prep1_kernel<<<256 + WT_NB, 256, 0, stream>>>(w1, hs, gw, w1t, hsb, eid, wgt, counts);
  scatter_kernel<<<NPAIR / 256, 256, 0, stream>>>(eid, counts, fill, rowmap, posmap);

  gemm0_w2t_kernel<<<G0_NWG + WT_NB, 256, 0, stream>>>(
      hsb, w1t, act, w2, w2t, counts, rowmap);
  moe_gemm1<<<MAX_RT * (H_DIM / BN), 256, 0, stream>>>(
      w2t, act, res, counts, rowmap, wgt);

  combine_kernel<<<T_TOK, 256, 0, stream>>>(res, posmap, out);
}